// Round 1
// baseline (4903.303 us; speedup 1.0000x reference)
//
#include <hip/hip_runtime.h>
#include <cstdint>

#define HID 256
#define HEADS 4
#define NPB 8          // nodes per block in GEMM kernels
#define GRAPHS 64
#define OUTC 32
#define EPSV 1e-5f

// ---------------- block LayerNorm stats (blockDim=256, 4 waves) ----------------
template<int NB>
__device__ __forceinline__ void block_ln_stats(const float* vals, float red[4][NB][2],
                                               float* mu, float* rstd)
{
    int tid = threadIdx.x;
    int lane = tid & 63, wv = tid >> 6;
    float s[NB], s2[NB];
#pragma unroll
    for (int j = 0; j < NB; j++) { s[j] = vals[j]; s2[j] = vals[j] * vals[j]; }
#pragma unroll
    for (int o = 1; o < 64; o <<= 1) {
#pragma unroll
        for (int j = 0; j < NB; j++) {
            s[j]  += __shfl_xor(s[j],  o, 64);
            s2[j] += __shfl_xor(s2[j], o, 64);
        }
    }
    if (lane == 0) {
#pragma unroll
        for (int j = 0; j < NB; j++) { red[wv][j][0] = s[j]; red[wv][j][1] = s2[j]; }
    }
    __syncthreads();
#pragma unroll
    for (int j = 0; j < NB; j++) {
        float sm = red[0][j][0] + red[1][j][0] + red[2][j][0] + red[3][j][0];
        float sq = red[0][j][1] + red[1][j][1] + red[2][j][1] + red[3][j][1];
        float m = sm * (1.f / HID);
        float v = sq * (1.f / HID) - m * m;
        mu[j] = m;
        rstd[j] = rsqrtf(v + EPSV);
    }
}

// ---------------- encoder stage 1: t = LN(relu(x @ W1 + b1)), K=128 ----------------
__global__ __launch_bounds__(256) void enc1_kernel(const float* __restrict__ x,
    const float* __restrict__ W, const float* __restrict__ b,
    const float* __restrict__ g, const float* __restrict__ be,
    float* __restrict__ out, int n)
{
    __shared__ float lin[NPB][128];
    __shared__ float red[4][NPB][2];
    int tid = threadIdx.x;
    int base = blockIdx.x * NPB;
    for (int i = tid; i < NPB * 128; i += 256) {
        int j = i >> 7, k = i & 127;
        int node = base + j;
        lin[j][k] = (node < n) ? x[(size_t)node * 128 + k] : 0.f;
    }
    __syncthreads();
    int c = tid;
    float acc[NPB];
#pragma unroll
    for (int j = 0; j < NPB; j++) acc[j] = 0.f;
    for (int k0 = 0; k0 < 128; k0 += 4) {
        float w0 = W[(k0 + 0) * HID + c], w1 = W[(k0 + 1) * HID + c];
        float w2 = W[(k0 + 2) * HID + c], w3 = W[(k0 + 3) * HID + c];
#pragma unroll
        for (int j = 0; j < NPB; j++) {
            float4 a = *(const float4*)&lin[j][k0];
            acc[j] += a.x * w0 + a.y * w1 + a.z * w2 + a.w * w3;
        }
    }
    float bb = b[c];
#pragma unroll
    for (int j = 0; j < NPB; j++) acc[j] = fmaxf(acc[j] + bb, 0.f);
    float mu[NPB], rs[NPB];
    block_ln_stats<NPB>(acc, red, mu, rs);
    float gg = g[c], bt = be[c];
#pragma unroll
    for (int j = 0; j < NPB; j++) {
        int node = base + j;
        if (node < n) out[(size_t)node * HID + c] = (acc[j] - mu[j]) * rs[j] * gg + bt;
    }
}

// ---------------- generic 256x256 GEMM with fused epilogues ----------------
template<bool RELU_LN, bool ADD_RES, bool POS>
__global__ __launch_bounds__(256) void gemm256_kernel(const float* __restrict__ in,
    const float* __restrict__ W, const float* __restrict__ b,
    const float* __restrict__ g, const float* __restrict__ be,
    const float* __restrict__ addsrc, const float* __restrict__ pos_emb,
    const int* __restrict__ pidx, float* __restrict__ out, int n)
{
    __shared__ float lin[NPB][HID];
    __shared__ float red[4][NPB][2];
    int tid = threadIdx.x;
    int base = blockIdx.x * NPB;
    for (int i = tid; i < NPB * HID; i += 256) {
        int j = i >> 8, k = i & 255;
        int node = base + j;
        lin[j][k] = (node < n) ? in[(size_t)node * HID + k] : 0.f;
    }
    __syncthreads();
    int c = tid;
    float acc[NPB];
#pragma unroll
    for (int j = 0; j < NPB; j++) acc[j] = 0.f;
    for (int k0 = 0; k0 < HID; k0 += 4) {
        float w0 = W[(k0 + 0) * HID + c], w1 = W[(k0 + 1) * HID + c];
        float w2 = W[(k0 + 2) * HID + c], w3 = W[(k0 + 3) * HID + c];
#pragma unroll
        for (int j = 0; j < NPB; j++) {
            float4 a = *(const float4*)&lin[j][k0];
            acc[j] += a.x * w0 + a.y * w1 + a.z * w2 + a.w * w3;
        }
    }
    float bb = b[c];
#pragma unroll
    for (int j = 0; j < NPB; j++) acc[j] += bb;
    if (RELU_LN) {
#pragma unroll
        for (int j = 0; j < NPB; j++) acc[j] = fmaxf(acc[j], 0.f);
        float mu[NPB], rs[NPB];
        block_ln_stats<NPB>(acc, red, mu, rs);
        float gg = g[c], bt = be[c];
#pragma unroll
        for (int j = 0; j < NPB; j++) acc[j] = (acc[j] - mu[j]) * rs[j] * gg + bt;
    }
#pragma unroll
    for (int j = 0; j < NPB; j++) {
        int node = base + j;
        if (node >= n) continue;
        float v = acc[j];
        if (ADD_RES) v += addsrc[(size_t)node * HID + c];
        if (POS)     v += pos_emb[(size_t)pidx[node] * HID + c];
        out[(size_t)node * HID + c] = v;
    }
}

// ---------------- fused QKV projection ----------------
__global__ __launch_bounds__(256) void qkv_kernel(const float* __restrict__ hsrc,
    const float* __restrict__ Wq, const float* __restrict__ bq,
    const float* __restrict__ Wk, const float* __restrict__ bk,
    const float* __restrict__ Wv, const float* __restrict__ bv,
    float* __restrict__ Qo, float* __restrict__ Ko, float* __restrict__ Vo, int n)
{
    __shared__ float lin[NPB][HID];
    int tid = threadIdx.x;
    int base = blockIdx.x * NPB;
    for (int i = tid; i < NPB * HID; i += 256) {
        int j = i >> 8, k = i & 255;
        int node = base + j;
        lin[j][k] = (node < n) ? hsrc[(size_t)node * HID + k] : 0.f;
    }
    __syncthreads();
    int c = tid;
    float aq[NPB], ak[NPB], av[NPB];
#pragma unroll
    for (int j = 0; j < NPB; j++) { aq[j] = 0.f; ak[j] = 0.f; av[j] = 0.f; }
    for (int k0 = 0; k0 < HID; k0 += 4) {
        float q0 = Wq[(k0 + 0) * HID + c], q1 = Wq[(k0 + 1) * HID + c];
        float q2 = Wq[(k0 + 2) * HID + c], q3 = Wq[(k0 + 3) * HID + c];
        float K0 = Wk[(k0 + 0) * HID + c], K1 = Wk[(k0 + 1) * HID + c];
        float K2 = Wk[(k0 + 2) * HID + c], K3 = Wk[(k0 + 3) * HID + c];
        float v0 = Wv[(k0 + 0) * HID + c], v1 = Wv[(k0 + 1) * HID + c];
        float v2 = Wv[(k0 + 2) * HID + c], v3 = Wv[(k0 + 3) * HID + c];
#pragma unroll
        for (int j = 0; j < NPB; j++) {
            float4 a = *(const float4*)&lin[j][k0];
            aq[j] += a.x * q0 + a.y * q1 + a.z * q2 + a.w * q3;
            ak[j] += a.x * K0 + a.y * K1 + a.z * K2 + a.w * K3;
            av[j] += a.x * v0 + a.y * v1 + a.z * v2 + a.w * v3;
        }
    }
    float bq_ = bq[c], bk_ = bk[c], bv_ = bv[c];
#pragma unroll
    for (int j = 0; j < NPB; j++) {
        int node = base + j;
        if (node >= n) continue;
        size_t o = (size_t)node * HID + c;
        Qo[o] = aq[j] + bq_;
        Ko[o] = ak[j] + bk_;
        Vo[o] = av[j] + bv_;
    }
}

// ---------------- MLP stage 1: t = LN(relu([h,agg] @ W1 + b1)), K=512 ----------------
__global__ __launch_bounds__(256) void mlp1_kernel(const float* __restrict__ h,
    const float* __restrict__ agg, const float* __restrict__ W,
    const float* __restrict__ b, const float* __restrict__ g,
    const float* __restrict__ be, float* __restrict__ out, int n)
{
    __shared__ float lin[NPB][HID];
    __shared__ float red[4][NPB][2];
    int tid = threadIdx.x;
    int base = blockIdx.x * NPB;
    int c = tid;
    float acc[NPB];
#pragma unroll
    for (int j = 0; j < NPB; j++) acc[j] = 0.f;
    for (int half = 0; half < 2; half++) {
        const float* src = half ? agg : h;
        const float* Wp = W + (size_t)half * HID * HID;
        __syncthreads();
        for (int i = tid; i < NPB * HID; i += 256) {
            int j = i >> 8, k = i & 255;
            int node = base + j;
            lin[j][k] = (node < n) ? src[(size_t)node * HID + k] : 0.f;
        }
        __syncthreads();
        for (int k0 = 0; k0 < HID; k0 += 4) {
            float w0 = Wp[(k0 + 0) * HID + c], w1 = Wp[(k0 + 1) * HID + c];
            float w2 = Wp[(k0 + 2) * HID + c], w3 = Wp[(k0 + 3) * HID + c];
#pragma unroll
            for (int j = 0; j < NPB; j++) {
                float4 a = *(const float4*)&lin[j][k0];
                acc[j] += a.x * w0 + a.y * w1 + a.z * w2 + a.w * w3;
            }
        }
    }
    float bb = b[c];
#pragma unroll
    for (int j = 0; j < NPB; j++) acc[j] = fmaxf(acc[j] + bb, 0.f);
    float mu[NPB], rs[NPB];
    block_ln_stats<NPB>(acc, red, mu, rs);
    float gg = g[c], bt = be[c];
#pragma unroll
    for (int j = 0; j < NPB; j++) {
        int node = base + j;
        if (node < n) out[(size_t)node * HID + c] = (acc[j] - mu[j]) * rs[j] * gg + bt;
    }
}

// ---------------- CSR build ----------------
__global__ void count_kernel(const int* __restrict__ row, int* __restrict__ counts, int e)
{
    int i = blockIdx.x * blockDim.x + threadIdx.x;
    if (i < e) atomicAdd(&counts[row[i]], 1);
}

__global__ __launch_bounds__(256) void scan1_kernel(const int* __restrict__ counts,
    int* __restrict__ offs, int* __restrict__ bsum, int n)
{
    __shared__ int wsumS[4];
    int tid = threadIdx.x, b = blockIdx.x;
    int i = b * 256 + tid;
    int v = (i < n) ? counts[i] : 0;
    int lane = tid & 63, wv = tid >> 6;
    int s = v;
#pragma unroll
    for (int o = 1; o < 64; o <<= 1) { int t = __shfl_up(s, o, 64); if (lane >= o) s += t; }
    if (lane == 63) wsumS[wv] = s;
    __syncthreads();
    int add = 0;
    for (int j = 0; j < wv; j++) add += wsumS[j];
    s += add;
    if (i < n) offs[i + 1] = s;
    if (tid == 255) bsum[b] = s;
}

__global__ __launch_bounds__(256) void scan2_kernel(int* __restrict__ bsum, int nb)
{
    __shared__ int wsumS[4];
    int tid = threadIdx.x;
    int v = (tid < nb) ? bsum[tid] : 0;
    int lane = tid & 63, wv = tid >> 6;
    int s = v;
#pragma unroll
    for (int o = 1; o < 64; o <<= 1) { int t = __shfl_up(s, o, 64); if (lane >= o) s += t; }
    if (lane == 63) wsumS[wv] = s;
    __syncthreads();
    int add = 0;
    for (int j = 0; j < wv; j++) add += wsumS[j];
    s += add;
    if (tid < nb) bsum[tid] = s;
}

__global__ __launch_bounds__(256) void scan3_kernel(int* __restrict__ offs,
    const int* __restrict__ bsum, int n)
{
    int tid = threadIdx.x, b = blockIdx.x;
    int i = b * 256 + tid;
    if (i == 0) offs[0] = 0;
    if (i < n && b > 0) offs[i + 1] += bsum[b - 1];
}

__global__ void scatter_kernel(const int* __restrict__ row, const int* __restrict__ col,
    const int* __restrict__ offs, int* __restrict__ cur, int* __restrict__ ccol, int e)
{
    int i = blockIdx.x * blockDim.x + threadIdx.x;
    if (i >= e) return;
    int r = row[i];
    int pos = atomicAdd(&cur[r], 1);
    ccol[offs[r] + pos] = col[i];
}

// ---------------- fused attention (scores + segment softmax + aggregate) ----------------
// one block (4 waves) per destination node; online softmax; no atomics.
// NOTE: agg may alias Qm — each block reads only its own Q row (hoisted) before writing agg row.
__global__ __launch_bounds__(256) void attn_kernel(const float* __restrict__ Qm,
    const float* __restrict__ Km, const float* __restrict__ Vm,
    const int* __restrict__ offs, const int* __restrict__ ccol,
    float* __restrict__ agg, int n)
{
    __shared__ float wredM[4][HEADS];
    __shared__ float wredD[4][HEADS];
    __shared__ float accT[4][HID];
    int node = blockIdx.x;
    int tid = threadIdx.x, lane = tid & 63, wv = tid >> 6;
    int grp = lane >> 4;             // head handled by this 16-lane group
    int start = offs[node], fin = offs[node + 1];
    int deg = fin - start;
    if (deg == 0) { agg[(size_t)node * HID + tid] = 0.f; return; }

    float4 qv = *(const float4*)(Qm + (size_t)node * HID + lane * 4);
    float m = -3.0e38f, d = 0.f;
    float4 acc = {0.f, 0.f, 0.f, 0.f};
    for (int i = start + wv; i < fin; i += 4) {
        int c = ccol[i];
        const float* kp = Km + (size_t)c * HID + lane * 4;
        const float* vp = Vm + (size_t)c * HID + lane * 4;
        float4 kv = *(const float4*)kp;
        float p = qv.x * kv.x + qv.y * kv.y + qv.z * kv.z + qv.w * kv.w;
        p += __shfl_xor(p, 1, 64);
        p += __shfl_xor(p, 2, 64);
        p += __shfl_xor(p, 4, 64);
        p += __shfl_xor(p, 8, 64);
        float s = p * 0.125f;                   // / sqrt(64)
        float mnew = fmaxf(m, s);
        float scalef = __expf(m - mnew);        // m=-3e38 first time -> 0
        float w = __expf(s - mnew);
        d = d * scalef + w;
        float4 vvv = *(const float4*)vp;
        acc.x = acc.x * scalef + w * vvv.x;
        acc.y = acc.y * scalef + w * vvv.y;
        acc.z = acc.z * scalef + w * vvv.z;
        acc.w = acc.w * scalef + w * vvv.w;
        m = mnew;
    }
    if ((lane & 15) == 0) { wredM[wv][grp] = m; wredD[wv][grp] = d; }
    __syncthreads();
    // per-head global max for this wave's head
    float M = fmaxf(fmaxf(wredM[0][grp], wredM[1][grp]), fmaxf(wredM[2][grp], wredM[3][grp]));
    float fac = __expf(m - M);                  // empty wave: exp(-3e38 - M) = 0
    acc.x *= fac; acc.y *= fac; acc.z *= fac; acc.w *= fac;
    *(float4*)&accT[wv][lane * 4] = acc;
    __syncthreads();
    int hh = tid >> 6;                          // head of output channel tid
    float M2 = fmaxf(fmaxf(wredM[0][hh], wredM[1][hh]), fmaxf(wredM[2][hh], wredM[3][hh]));
    float D = wredD[0][hh] * __expf(wredM[0][hh] - M2)
            + wredD[1][hh] * __expf(wredM[1][hh] - M2)
            + wredD[2][hh] * __expf(wredM[2][hh] - M2)
            + wredD[3][hh] * __expf(wredM[3][hh] - M2);
    float r = accT[0][tid] + accT[1][tid] + accT[2][tid] + accT[3][tid];
    agg[(size_t)node * HID + tid] = r / D;
}

// ---------------- pooling ----------------
__global__ void bounds_kernel(const int* __restrict__ batch, int* __restrict__ gb, int n)
{
    int g = threadIdx.x;
    if (g > GRAPHS) return;
    int lo = 0, hi = n;
    while (lo < hi) { int mid = (lo + hi) >> 1; if (batch[mid] < g) lo = mid + 1; else hi = mid; }
    gb[g] = lo;
}

__global__ __launch_bounds__(256) void pool_kernel(const float* __restrict__ h,
    const int* __restrict__ gb, float* __restrict__ pooled)
{
    int g = blockIdx.x, tid = threadIdx.x;
    int s = gb[g], e = gb[g + 1];
    float sum = 0.f;
    for (int i = s; i < e; i++) sum += h[(size_t)i * HID + tid];
    pooled[g * HID + tid] = sum / fmaxf((float)(e - s), 1.f);
}

// ---------------- classifier ----------------
__global__ __launch_bounds__(256) void cls_kernel(const float* __restrict__ pooled,
    const float* __restrict__ W1, const float* __restrict__ b1,
    const float* __restrict__ g, const float* __restrict__ be,
    const float* __restrict__ W2, const float* __restrict__ b2,
    float* __restrict__ out)
{
    __shared__ float pin[HID];
    __shared__ float hbuf[HID];
    __shared__ float red[4][1][2];
    int tid = threadIdx.x, gi = blockIdx.x;
    pin[tid] = pooled[gi * HID + tid];
    __syncthreads();
    float acc = 0.f;
    for (int k = 0; k < HID; k++) acc += pin[k] * W1[k * HID + tid];
    acc = fmaxf(acc + b1[tid], 0.f);
    float v[1] = {acc}, mu[1], rs[1];
    block_ln_stats<1>(v, red, mu, rs);
    hbuf[tid] = (acc - mu[0]) * rs[0] * g[tid] + be[tid];
    __syncthreads();
    if (tid < OUTC) {
        float o = 0.f;
        for (int k = 0; k < HID; k++) o += hbuf[k] * W2[k * OUTC + tid];
        out[gi * OUTC + tid] = o + b2[tid];
    }
}

// ---------------- host launch ----------------
extern "C" void kernel_launch(void* const* d_in, const int* in_sizes, int n_in,
                              void* d_out, int out_size, void* d_ws, size_t ws_size,
                              hipStream_t stream)
{
    const float* x        = (const float*)d_in[0];
    const int*   ei       = (const int*)d_in[1];
    const int*   pidx     = (const int*)d_in[2];
    const int*   batch    = (const int*)d_in[3];
    const float* enc_w1   = (const float*)d_in[4];
    const float* enc_b1   = (const float*)d_in[5];
    const float* enc_g    = (const float*)d_in[6];
    const float* enc_beta = (const float*)d_in[7];
    const float* enc_w2   = (const float*)d_in[8];
    const float* enc_b2   = (const float*)d_in[9];
    const float* pos_emb  = (const float*)d_in[10];
    const float* Wq       = (const float*)d_in[11];
    const float* bq       = (const float*)d_in[12];
    const float* Wk       = (const float*)d_in[13];
    const float* bk       = (const float*)d_in[14];
    const float* Wv       = (const float*)d_in[15];
    const float* bv       = (const float*)d_in[16];
    const float* mlp_w1   = (const float*)d_in[17];
    const float* mlp_b1   = (const float*)d_in[18];
    const float* mlp_g    = (const float*)d_in[19];
    const float* mlp_beta = (const float*)d_in[20];
    const float* mlp_w2   = (const float*)d_in[21];
    const float* mlp_b2   = (const float*)d_in[22];
    const float* cls_w1   = (const float*)d_in[23];
    const float* cls_b1   = (const float*)d_in[24];
    const float* cls_g    = (const float*)d_in[25];
    const float* cls_beta = (const float*)d_in[26];
    const float* cls_w2   = (const float*)d_in[27];
    const float* cls_b2   = (const float*)d_in[28];

    int n = in_sizes[2];            // 50000
    int e = in_sizes[1] / 2;        // 800000
    const int* row = ei;
    const int* col = ei + e;

    // workspace carve (16B+ aligned)
    char* p = (char*)d_ws;
    auto alloc = [&](size_t bytes) -> void* {
        void* r = (void*)p;
        p += (bytes + 255) & ~(size_t)255;
        return r;
    };
    size_t NH = (size_t)n * HID;
    float* h   = (float*)alloc(NH * 4);
    float* t   = (float*)alloc(NH * 4);   // enc hidden / Q / agg
    float* Kb  = (float*)alloc(NH * 4);   // K / mlp hidden
    float* Vb  = (float*)alloc(NH * 4);   // V
    float* pooled = (float*)alloc(GRAPHS * HID * 4);
    int* counts = (int*)alloc((size_t)n * 4);
    int* offs   = (int*)alloc((size_t)(n + 1) * 4);
    int* cur    = (int*)alloc((size_t)n * 4);
    int* ccol   = (int*)alloc((size_t)e * 4);
    int* bsum   = (int*)alloc(1024);
    int* gb     = (int*)alloc((GRAPHS + 1) * 4);

    int gemm_blocks = (n + NPB - 1) / NPB;
    int nb = (n + 255) / 256;

    // ---- CSR build (once; edge structure is layer-invariant) ----
    hipMemsetAsync(counts, 0, (size_t)n * 4, stream);
    hipMemsetAsync(cur, 0, (size_t)n * 4, stream);
    count_kernel<<<(e + 255) / 256, 256, 0, stream>>>(row, counts, e);
    scan1_kernel<<<nb, 256, 0, stream>>>(counts, offs, bsum, n);
    scan2_kernel<<<1, 256, 0, stream>>>(bsum, nb);
    scan3_kernel<<<nb, 256, 0, stream>>>(offs, bsum, n);
    scatter_kernel<<<(e + 255) / 256, 256, 0, stream>>>(row, col, offs, cur, ccol, e);

    // ---- encoder ----
    enc1_kernel<<<gemm_blocks, 256, 0, stream>>>(x, enc_w1, enc_b1, enc_g, enc_beta, t, n);
    gemm256_kernel<false, false, true><<<gemm_blocks, 256, 0, stream>>>(
        t, enc_w2, enc_b2, nullptr, nullptr, nullptr, pos_emb, pidx, h, n);

    // ---- attention layers ----
    for (int l = 0; l < 4; l++) {
        size_t wo = (size_t)l * HID * HID;
        size_t bo = (size_t)l * HID;
        qkv_kernel<<<gemm_blocks, 256, 0, stream>>>(
            h, Wq + wo, bq + bo, Wk + wo, bk + bo, Wv + wo, bv + bo,
            t, Kb, Vb, n);
        attn_kernel<<<n, 256, 0, stream>>>(t, Kb, Vb, offs, ccol, t /*agg aliases Q*/, n);
        mlp1_kernel<<<gemm_blocks, 256, 0, stream>>>(
            h, t, mlp_w1 + (size_t)l * 2 * HID * HID, mlp_b1 + bo,
            mlp_g + bo, mlp_beta + bo, Kb, n);
        gemm256_kernel<false, true, false><<<gemm_blocks, 256, 0, stream>>>(
            Kb, mlp_w2 + wo, mlp_b2 + bo, nullptr, nullptr, h, nullptr, nullptr, h, n);
    }

    // ---- pool + classifier ----
    bounds_kernel<<<1, 128, 0, stream>>>(batch, gb, n);
    pool_kernel<<<GRAPHS, 256, 0, stream>>>(h, gb, pooled);
    cls_kernel<<<GRAPHS, 256, 0, stream>>>(pooled, cls_w1, cls_b1, cls_g, cls_beta,
                                           cls_w2, cls_b2, (float*)d_out);
}

// Round 2
// 2319.627 us; speedup vs baseline: 2.1138x; 2.1138x over previous
//
#include <hip/hip_runtime.h>
#include <cstdint>

#define HID 256
#define HEADS 4
#define GRAPHS 64
#define OUTC 32
#define EPSV 1e-5f

typedef __bf16 b16x8 __attribute__((ext_vector_type(8)));
typedef float  f32x4 __attribute__((ext_vector_type(4)));

__device__ __forceinline__ f32x4 mfma16(b16x8 a, b16x8 b, f32x4 c) {
    return __builtin_amdgcn_mfma_f32_16x16x32_bf16(a, b, c, 0, 0, 0);
}

__device__ __forceinline__ unsigned int pack_bf16(float a, float b) {
    unsigned short ua = __builtin_bit_cast(unsigned short, (__bf16)a);
    unsigned short ub = __builtin_bit_cast(unsigned short, (__bf16)b);
    return (unsigned int)ua | ((unsigned int)ub << 16);
}

// ---------------- weight transpose + bf16 convert: W[K][C] -> Wt[C][K] ----------------
__global__ __launch_bounds__(256) void wtrans_kernel(const float* __restrict__ W,
    unsigned short* __restrict__ Wt, int K, int C)
{
    __shared__ float tile[32][33];
    const float* Wm = W + (size_t)blockIdx.z * K * C;
    unsigned short* Wtm = Wt + (size_t)blockIdx.z * K * C;
    int k0 = blockIdx.x * 32, c0 = blockIdx.y * 32;
    int tx = threadIdx.x & 31, ty = threadIdx.x >> 5;
#pragma unroll
    for (int i = 0; i < 32; i += 8)
        tile[ty + i][tx] = Wm[(size_t)(k0 + ty + i) * C + c0 + tx];
    __syncthreads();
#pragma unroll
    for (int i = 0; i < 32; i += 8) {
        float v = tile[tx][ty + i];
        Wtm[(size_t)(c0 + ty + i) * K + k0 + tx] =
            __builtin_bit_cast(unsigned short, (__bf16)v);
    }
}

// ---------------- MFMA GEMM: out[n,256] = epi(in[n,K] @ W[K,256] + b) ----------------
// block: 64 rows x 256 cols, 4 waves (each 64x64). A staged in LDS (bf16, XOR-swizzled),
// B fragments read from pre-transposed bf16 Wt[col][k] in global (L2-resident).
template<int KTILE, int NPASS, bool RELU_LN, bool ADD_RES, bool POS>
__global__ __launch_bounds__(256) void gemm_mfma(
    const float* __restrict__ in0, const float* __restrict__ in1,
    const unsigned short* __restrict__ Wt, const float* __restrict__ bias,
    const float* __restrict__ g, const float* __restrict__ be,
    const float* __restrict__ addsrc, const float* __restrict__ pos_emb,
    const int* __restrict__ pidx, float* __restrict__ out, int n)
{
    constexpr int KS = KTILE * NPASS;        // Wt row stride
    constexpr int ROWB = KTILE * 2;          // LDS row bytes
    __shared__ __align__(16) char alds[64 * KTILE * 2];
    __shared__ float red[4][64][2];

    int tid = threadIdx.x, lane = tid & 63, wv = tid >> 6;
    int cg = lane & 15, rg = lane >> 4;
    int base = blockIdx.x * 64;
    int cbase = wv * 64;

    f32x4 acc[4][4];
#pragma unroll
    for (int m = 0; m < 4; m++)
#pragma unroll
        for (int f = 0; f < 4; f++) acc[m][f] = (f32x4){0.f, 0.f, 0.f, 0.f};

    for (int pass = 0; pass < NPASS; pass++) {
        if (pass) __syncthreads();
        const float* src = pass ? in1 : in0;
        // stage A: 64 x KTILE fp32 -> bf16 LDS, swizzled
        constexpr int ITERS = (64 * KTILE) / (256 * 4);
#pragma unroll
        for (int i = 0; i < ITERS; i++) {
            int idx = (i * 256 + tid) * 4;
            int row = idx / KTILE;
            int k = idx & (KTILE - 1);
            int node = base + row;
            float4 v = {0.f, 0.f, 0.f, 0.f};
            if (node < n) v = *(const float4*)(src + (size_t)node * KTILE + k);
            uint2 pp;
            pp.x = pack_bf16(v.x, v.y);
            pp.y = pack_bf16(v.z, v.w);
            int off = row * ROWB + k * 2;
            off ^= (row & 7) << 4;
            *(uint2*)(alds + off) = pp;
        }
        __syncthreads();

        const unsigned short* Wp = Wt + pass * KTILE;
#pragma unroll 2
        for (int k0 = 0; k0 < KTILE; k0 += 32) {
            b16x8 a[4], b[4];
#pragma unroll
            for (int m = 0; m < 4; m++) {
                int R = m * 16 + cg;
                int off = R * ROWB + (k0 + rg * 8) * 2;
                off ^= (R & 7) << 4;
                uint4 u = *(const uint4*)(alds + off);
                a[m] = __builtin_bit_cast(b16x8, u);
            }
#pragma unroll
            for (int f = 0; f < 4; f++) {
                const unsigned short* p = Wp + (size_t)(cbase + f * 16 + cg) * KS + k0 + rg * 8;
                uint4 u = *(const uint4*)p;
                b[f] = __builtin_bit_cast(b16x8, u);
            }
#pragma unroll
            for (int m = 0; m < 4; m++)
#pragma unroll
                for (int f = 0; f < 4; f++)
                    acc[m][f] = mfma16(a[m], b[f], acc[m][f]);
        }
    }

    // epilogue
    float bias_v[4], g_v[4], be_v[4];
#pragma unroll
    for (int f = 0; f < 4; f++) {
        int col = cbase + f * 16 + cg;
        bias_v[f] = bias[col];
        if (RELU_LN) { g_v[f] = g[col]; be_v[f] = be[col]; }
    }
#pragma unroll
    for (int m = 0; m < 4; m++)
#pragma unroll
        for (int f = 0; f < 4; f++)
#pragma unroll
            for (int r = 0; r < 4; r++) acc[m][f][r] += bias_v[f];

    if (RELU_LN) {
#pragma unroll
        for (int m = 0; m < 4; m++)
#pragma unroll
            for (int f = 0; f < 4; f++)
#pragma unroll
                for (int r = 0; r < 4; r++) acc[m][f][r] = fmaxf(acc[m][f][r], 0.f);
        // per-row stats over 256 cols: in-lane over f, shfl over 16 lanes, LDS over 4 waves
#pragma unroll
        for (int m = 0; m < 4; m++)
#pragma unroll
            for (int r = 0; r < 4; r++) {
                float s = acc[m][0][r] + acc[m][1][r] + acc[m][2][r] + acc[m][3][r];
                float q = acc[m][0][r] * acc[m][0][r] + acc[m][1][r] * acc[m][1][r]
                        + acc[m][2][r] * acc[m][2][r] + acc[m][3][r] * acc[m][3][r];
#pragma unroll
                for (int o = 1; o < 16; o <<= 1) {
                    s += __shfl_xor(s, o, 64);
                    q += __shfl_xor(q, o, 64);
                }
                if (cg == 0) {
                    int R = m * 16 + rg * 4 + r;
                    red[wv][R][0] = s;
                    red[wv][R][1] = q;
                }
            }
        __syncthreads();
#pragma unroll
        for (int m = 0; m < 4; m++)
#pragma unroll
            for (int r = 0; r < 4; r++) {
                int R = m * 16 + rg * 4 + r;
                float S = red[0][R][0] + red[1][R][0] + red[2][R][0] + red[3][R][0];
                float Q = red[0][R][1] + red[1][R][1] + red[2][R][1] + red[3][R][1];
                float mu = S * (1.f / HID);
                float var = Q * (1.f / HID) - mu * mu;
                float rs = rsqrtf(var + EPSV);
#pragma unroll
                for (int f = 0; f < 4; f++)
                    acc[m][f][r] = (acc[m][f][r] - mu) * rs * g_v[f] + be_v[f];
            }
    }

    // store
#pragma unroll
    for (int m = 0; m < 4; m++)
#pragma unroll
        for (int r = 0; r < 4; r++) {
            int row = base + m * 16 + rg * 4 + r;
            if (row >= n) continue;
            size_t ro = (size_t)row * HID;
            int pid = 0;
            if (POS) pid = pidx[row];
#pragma unroll
            for (int f = 0; f < 4; f++) {
                int col = cbase + f * 16 + cg;
                float v = acc[m][f][r];
                if (ADD_RES) v += addsrc[ro + col];
                if (POS)     v += pos_emb[(size_t)pid * HID + col];
                out[ro + col] = v;
            }
        }
}

// ---------------- CSR build ----------------
__global__ void count_kernel(const int* __restrict__ row, int* __restrict__ counts, int e)
{
    int i = blockIdx.x * blockDim.x + threadIdx.x;
    if (i < e) atomicAdd(&counts[row[i]], 1);
}

__global__ __launch_bounds__(256) void scan1_kernel(const int* __restrict__ counts,
    int* __restrict__ offs, int* __restrict__ bsum, int n)
{
    __shared__ int wsumS[4];
    int tid = threadIdx.x, b = blockIdx.x;
    int i = b * 256 + tid;
    int v = (i < n) ? counts[i] : 0;
    int lane = tid & 63, wv = tid >> 6;
    int s = v;
#pragma unroll
    for (int o = 1; o < 64; o <<= 1) { int t = __shfl_up(s, o, 64); if (lane >= o) s += t; }
    if (lane == 63) wsumS[wv] = s;
    __syncthreads();
    int add = 0;
    for (int j = 0; j < wv; j++) add += wsumS[j];
    s += add;
    if (i < n) offs[i + 1] = s;
    if (tid == 255) bsum[b] = s;
}

__global__ __launch_bounds__(256) void scan2_kernel(int* __restrict__ bsum, int nb)
{
    __shared__ int wsumS[4];
    int tid = threadIdx.x;
    int v = (tid < nb) ? bsum[tid] : 0;
    int lane = tid & 63, wv = tid >> 6;
    int s = v;
#pragma unroll
    for (int o = 1; o < 64; o <<= 1) { int t = __shfl_up(s, o, 64); if (lane >= o) s += t; }
    if (lane == 63) wsumS[wv] = s;
    __syncthreads();
    int add = 0;
    for (int j = 0; j < wv; j++) add += wsumS[j];
    s += add;
    if (tid < nb) bsum[tid] = s;
}

__global__ __launch_bounds__(256) void scan3_kernel(int* __restrict__ offs,
    const int* __restrict__ bsum, int n)
{
    int tid = threadIdx.x, b = blockIdx.x;
    int i = b * 256 + tid;
    if (i == 0) offs[0] = 0;
    if (i < n && b > 0) offs[i + 1] += bsum[b - 1];
}

__global__ void scatter_kernel(const int* __restrict__ row, const int* __restrict__ col,
    const int* __restrict__ offs, int* __restrict__ cur, int* __restrict__ ccol, int e)
{
    int i = blockIdx.x * blockDim.x + threadIdx.x;
    if (i >= e) return;
    int r = row[i];
    int pos = atomicAdd(&cur[r], 1);
    ccol[offs[r] + pos] = col[i];
}

// ---------------- fused attention (scores + segment softmax + aggregate) ----------------
__global__ __launch_bounds__(256) void attn_kernel(const float* __restrict__ Qm,
    const float* __restrict__ Km, const float* __restrict__ Vm,
    const int* __restrict__ offs, const int* __restrict__ ccol,
    float* __restrict__ agg, int n)
{
    __shared__ float wredM[4][HEADS];
    __shared__ float wredD[4][HEADS];
    __shared__ float accT[4][HID];
    int node = blockIdx.x;
    int tid = threadIdx.x, lane = tid & 63, wv = tid >> 6;
    int grp = lane >> 4;
    int start = offs[node], fin = offs[node + 1];
    int deg = fin - start;
    if (deg == 0) { agg[(size_t)node * HID + tid] = 0.f; return; }

    float4 qv = *(const float4*)(Qm + (size_t)node * HID + lane * 4);
    float m = -3.0e38f, d = 0.f;
    float4 acc = {0.f, 0.f, 0.f, 0.f};
    for (int i = start + wv; i < fin; i += 4) {
        int c = ccol[i];
        const float* kp = Km + (size_t)c * HID + lane * 4;
        const float* vp = Vm + (size_t)c * HID + lane * 4;
        float4 kv = *(const float4*)kp;
        float p = qv.x * kv.x + qv.y * kv.y + qv.z * kv.z + qv.w * kv.w;
        p += __shfl_xor(p, 1, 64);
        p += __shfl_xor(p, 2, 64);
        p += __shfl_xor(p, 4, 64);
        p += __shfl_xor(p, 8, 64);
        float s = p * 0.125f;
        float mnew = fmaxf(m, s);
        float scalef = __expf(m - mnew);
        float w = __expf(s - mnew);
        d = d * scalef + w;
        float4 vvv = *(const float4*)vp;
        acc.x = acc.x * scalef + w * vvv.x;
        acc.y = acc.y * scalef + w * vvv.y;
        acc.z = acc.z * scalef + w * vvv.z;
        acc.w = acc.w * scalef + w * vvv.w;
        m = mnew;
    }
    if ((lane & 15) == 0) { wredM[wv][grp] = m; wredD[wv][grp] = d; }
    __syncthreads();
    float M = fmaxf(fmaxf(wredM[0][grp], wredM[1][grp]), fmaxf(wredM[2][grp], wredM[3][grp]));
    float fac = __expf(m - M);
    acc.x *= fac; acc.y *= fac; acc.z *= fac; acc.w *= fac;
    *(float4*)&accT[wv][lane * 4] = acc;
    __syncthreads();
    int hh = tid >> 6;
    float M2 = fmaxf(fmaxf(wredM[0][hh], wredM[1][hh]), fmaxf(wredM[2][hh], wredM[3][hh]));
    float D = wredD[0][hh] * __expf(wredM[0][hh] - M2)
            + wredD[1][hh] * __expf(wredM[1][hh] - M2)
            + wredD[2][hh] * __expf(wredM[2][hh] - M2)
            + wredD[3][hh] * __expf(wredM[3][hh] - M2);
    float r = accT[0][tid] + accT[1][tid] + accT[2][tid] + accT[3][tid];
    agg[(size_t)node * HID + tid] = r / D;
}

// ---------------- pooling ----------------
__global__ void bounds_kernel(const int* __restrict__ batch, int* __restrict__ gb, int n)
{
    int g = threadIdx.x;
    if (g > GRAPHS) return;
    int lo = 0, hi = n;
    while (lo < hi) { int mid = (lo + hi) >> 1; if (batch[mid] < g) lo = mid + 1; else hi = mid; }
    gb[g] = lo;
}

__global__ __launch_bounds__(256) void pool_kernel(const float* __restrict__ h,
    const int* __restrict__ gb, float* __restrict__ pooled)
{
    int g = blockIdx.x, tid = threadIdx.x;
    int s = gb[g], e = gb[g + 1];
    float sum = 0.f;
    for (int i = s; i < e; i++) sum += h[(size_t)i * HID + tid];
    pooled[g * HID + tid] = sum / fmaxf((float)(e - s), 1.f);
}

// ---------------- classifier ----------------
__global__ __launch_bounds__(256) void cls_kernel(const float* __restrict__ pooled,
    const float* __restrict__ W1, const float* __restrict__ b1,
    const float* __restrict__ g, const float* __restrict__ be,
    const float* __restrict__ W2, const float* __restrict__ b2,
    float* __restrict__ out)
{
    __shared__ float pin[HID];
    __shared__ float hbuf[HID];
    __shared__ float red2[4][2];
    int tid = threadIdx.x, gi = blockIdx.x;
    int lane = tid & 63, wv = tid >> 6;
    pin[tid] = pooled[gi * HID + tid];
    __syncthreads();
    float acc = 0.f;
    for (int k = 0; k < HID; k++) acc += pin[k] * W1[k * HID + tid];
    acc = fmaxf(acc + b1[tid], 0.f);
    float s = acc, q = acc * acc;
#pragma unroll
    for (int o = 1; o < 64; o <<= 1) { s += __shfl_xor(s, o, 64); q += __shfl_xor(q, o, 64); }
    if (lane == 0) { red2[wv][0] = s; red2[wv][1] = q; }
    __syncthreads();
    float S = red2[0][0] + red2[1][0] + red2[2][0] + red2[3][0];
    float Q = red2[0][1] + red2[1][1] + red2[2][1] + red2[3][1];
    float mu = S * (1.f / HID);
    float rs = rsqrtf(Q * (1.f / HID) - mu * mu + EPSV);
    hbuf[tid] = (acc - mu) * rs * g[tid] + be[tid];
    __syncthreads();
    if (tid < OUTC) {
        float o = 0.f;
        for (int k = 0; k < HID; k++) o += hbuf[k] * W2[k * OUTC + tid];
        out[gi * OUTC + tid] = o + b2[tid];
    }
}

// ---------------- host launch ----------------
extern "C" void kernel_launch(void* const* d_in, const int* in_sizes, int n_in,
                              void* d_out, int out_size, void* d_ws, size_t ws_size,
                              hipStream_t stream)
{
    const float* x        = (const float*)d_in[0];
    const int*   ei       = (const int*)d_in[1];
    const int*   pidx     = (const int*)d_in[2];
    const int*   batch    = (const int*)d_in[3];
    const float* enc_w1   = (const float*)d_in[4];
    const float* enc_b1   = (const float*)d_in[5];
    const float* enc_g    = (const float*)d_in[6];
    const float* enc_beta = (const float*)d_in[7];
    const float* enc_w2   = (const float*)d_in[8];
    const float* enc_b2   = (const float*)d_in[9];
    const float* pos_emb  = (const float*)d_in[10];
    const float* Wq       = (const float*)d_in[11];
    const float* bq       = (const float*)d_in[12];
    const float* Wk       = (const float*)d_in[13];
    const float* bk       = (const float*)d_in[14];
    const float* Wv       = (const float*)d_in[15];
    const float* bv       = (const float*)d_in[16];
    const float* mlp_w1   = (const float*)d_in[17];
    const float* mlp_b1   = (const float*)d_in[18];
    const float* mlp_g    = (const float*)d_in[19];
    const float* mlp_beta = (const float*)d_in[20];
    const float* mlp_w2   = (const float*)d_in[21];
    const float* mlp_b2   = (const float*)d_in[22];
    const float* cls_w1   = (const float*)d_in[23];
    const float* cls_b1   = (const float*)d_in[24];
    const float* cls_g    = (const float*)d_in[25];
    const float* cls_beta = (const float*)d_in[26];
    const float* cls_w2   = (const float*)d_in[27];
    const float* cls_b2   = (const float*)d_in[28];

    int n = in_sizes[2];            // 50000
    int e = in_sizes[1] / 2;        // 800000
    const int* row = ei;
    const int* col = ei + e;

    char* p = (char*)d_ws;
    auto alloc = [&](size_t bytes) -> void* {
        void* r = (void*)p;
        p += (bytes + 255) & ~(size_t)255;
        return r;
    };
    size_t NH = (size_t)n * HID;
    float* h   = (float*)alloc(NH * 4);
    float* t   = (float*)alloc(NH * 4);   // enc hidden / Q / agg
    float* Kb  = (float*)alloc(NH * 4);   // K / mlp hidden
    float* Vb  = (float*)alloc(NH * 4);   // V
    float* pooled = (float*)alloc(GRAPHS * HID * 4);
    int* counts = (int*)alloc((size_t)n * 4);
    int* offs   = (int*)alloc((size_t)(n + 1) * 4);
    int* cur    = (int*)alloc((size_t)n * 4);
    int* ccol   = (int*)alloc((size_t)e * 4);
    int* bsum   = (int*)alloc(1024);
    int* gb     = (int*)alloc((GRAPHS + 1) * 4);
    // bf16 transposed weights
    unsigned short* wt_e1 = (unsigned short*)alloc((size_t)128 * 256 * 2);
    unsigned short* wt_e2 = (unsigned short*)alloc((size_t)256 * 256 * 2);
    unsigned short* wt_q  = (unsigned short*)alloc((size_t)4 * 256 * 256 * 2);
    unsigned short* wt_k  = (unsigned short*)alloc((size_t)4 * 256 * 256 * 2);
    unsigned short* wt_v  = (unsigned short*)alloc((size_t)4 * 256 * 256 * 2);
    unsigned short* wt_m1 = (unsigned short*)alloc((size_t)4 * 512 * 256 * 2);
    unsigned short* wt_m2 = (unsigned short*)alloc((size_t)4 * 256 * 256 * 2);

    int gblocks = (n + 63) / 64;
    int nb = (n + 255) / 256;

    // ---- weight prep (bf16 transposed) ----
    wtrans_kernel<<<dim3(4, 8, 1),  256, 0, stream>>>(enc_w1, wt_e1, 128, 256);
    wtrans_kernel<<<dim3(8, 8, 1),  256, 0, stream>>>(enc_w2, wt_e2, 256, 256);
    wtrans_kernel<<<dim3(8, 8, 4),  256, 0, stream>>>(Wq,     wt_q,  256, 256);
    wtrans_kernel<<<dim3(8, 8, 4),  256, 0, stream>>>(Wk,     wt_k,  256, 256);
    wtrans_kernel<<<dim3(8, 8, 4),  256, 0, stream>>>(Wv,     wt_v,  256, 256);
    wtrans_kernel<<<dim3(16, 8, 4), 256, 0, stream>>>(mlp_w1, wt_m1, 512, 256);
    wtrans_kernel<<<dim3(8, 8, 4),  256, 0, stream>>>(mlp_w2, wt_m2, 256, 256);

    // ---- CSR build ----
    hipMemsetAsync(counts, 0, (size_t)n * 4, stream);
    hipMemsetAsync(cur, 0, (size_t)n * 4, stream);
    count_kernel<<<(e + 255) / 256, 256, 0, stream>>>(row, counts, e);
    scan1_kernel<<<nb, 256, 0, stream>>>(counts, offs, bsum, n);
    scan2_kernel<<<1, 256, 0, stream>>>(bsum, nb);
    scan3_kernel<<<nb, 256, 0, stream>>>(offs, bsum, n);
    scatter_kernel<<<(e + 255) / 256, 256, 0, stream>>>(row, col, offs, cur, ccol, e);

    // ---- encoder ----
    gemm_mfma<128, 1, true, false, false><<<gblocks, 256, 0, stream>>>(
        x, nullptr, wt_e1, enc_b1, enc_g, enc_beta, nullptr, nullptr, nullptr, t, n);
    gemm_mfma<256, 1, false, false, true><<<gblocks, 256, 0, stream>>>(
        t, nullptr, wt_e2, enc_b2, nullptr, nullptr, nullptr, pos_emb, pidx, h, n);

    // ---- attention layers ----
    for (int l = 0; l < 4; l++) {
        size_t wo = (size_t)l * 256 * 256;
        size_t bo = (size_t)l * HID;
        gemm_mfma<256, 1, false, false, false><<<gblocks, 256, 0, stream>>>(
            h, nullptr, wt_q + wo, bq + bo, nullptr, nullptr, nullptr, nullptr, nullptr, t, n);
        gemm_mfma<256, 1, false, false, false><<<gblocks, 256, 0, stream>>>(
            h, nullptr, wt_k + wo, bk + bo, nullptr, nullptr, nullptr, nullptr, nullptr, Kb, n);
        gemm_mfma<256, 1, false, false, false><<<gblocks, 256, 0, stream>>>(
            h, nullptr, wt_v + wo, bv + bo, nullptr, nullptr, nullptr, nullptr, nullptr, Vb, n);
        attn_kernel<<<n, 256, 0, stream>>>(t, Kb, Vb, offs, ccol, t /*agg aliases Q*/, n);
        gemm_mfma<256, 2, true, false, false><<<gblocks, 256, 0, stream>>>(
            h, t, wt_m1 + (size_t)l * 512 * 256, mlp_b1 + bo,
            mlp_g + bo, mlp_beta + bo, nullptr, nullptr, nullptr, Kb, n);
        gemm_mfma<256, 1, false, true, false><<<gblocks, 256, 0, stream>>>(
            Kb, nullptr, wt_m2 + wo, mlp_b2 + bo, nullptr, nullptr, h, nullptr, nullptr, h, n);
    }

    // ---- pool + classifier ----
    bounds_kernel<<<1, 128, 0, stream>>>(batch, gb, n);
    pool_kernel<<<GRAPHS, 256, 0, stream>>>(h, gb, pooled);
    cls_kernel<<<GRAPHS, 256, 0, stream>>>(pooled, cls_w1, cls_b1, cls_g, cls_beta,
                                           cls_w2, cls_b2, (float*)d_out);
}

// Round 3
// 1714.538 us; speedup vs baseline: 2.8598x; 1.3529x over previous
//
#include <hip/hip_runtime.h>
#include <cstdint>

#define HID 256
#define HEADS 4
#define GRAPHS 64
#define OUTC 32
#define EPSV 1e-5f

typedef __bf16 b16x8 __attribute__((ext_vector_type(8)));
typedef float  f32x4 __attribute__((ext_vector_type(4)));

__device__ __forceinline__ f32x4 mfma16(b16x8 a, b16x8 b, f32x4 c) {
    return __builtin_amdgcn_mfma_f32_16x16x32_bf16(a, b, c, 0, 0, 0);
}

__device__ __forceinline__ unsigned int pack_bf16(float a, float b) {
    unsigned short ua = __builtin_bit_cast(unsigned short, (__bf16)a);
    unsigned short ub = __builtin_bit_cast(unsigned short, (__bf16)b);
    return (unsigned int)ua | ((unsigned int)ub << 16);
}

__device__ __forceinline__ void unpack2(unsigned int u, float& lo, float& hi) {
    lo = __builtin_bit_cast(float, u << 16);
    hi = __builtin_bit_cast(float, u & 0xffff0000u);
}

// ---------------- weight transpose + bf16 convert: W[K][C] -> Wt[C][K] ----------------
__global__ __launch_bounds__(256) void wtrans_kernel(const float* __restrict__ W,
    unsigned short* __restrict__ Wt, int K, int C)
{
    __shared__ float tile[32][33];
    const float* Wm = W + (size_t)blockIdx.z * K * C;
    unsigned short* Wtm = Wt + (size_t)blockIdx.z * K * C;
    int k0 = blockIdx.x * 32, c0 = blockIdx.y * 32;
    int tx = threadIdx.x & 31, ty = threadIdx.x >> 5;
#pragma unroll
    for (int i = 0; i < 32; i += 8)
        tile[ty + i][tx] = Wm[(size_t)(k0 + ty + i) * C + c0 + tx];
    __syncthreads();
#pragma unroll
    for (int i = 0; i < 32; i += 8) {
        float v = tile[tx][ty + i];
        Wtm[(size_t)(c0 + ty + i) * K + k0 + tx] =
            __builtin_bit_cast(unsigned short, (__bf16)v);
    }
}

// ---------------- MFMA GEMM: out[n,256] = epi(in[n,K] @ W[K,256] + b), fp32 out ----------------
template<int KTILE, int NPASS, bool RELU_LN, bool ADD_RES, bool POS>
__global__ __launch_bounds__(256) void gemm_mfma(
    const float* __restrict__ in0, const float* __restrict__ in1,
    const unsigned short* __restrict__ Wt, const float* __restrict__ bias,
    const float* __restrict__ g, const float* __restrict__ be,
    const float* __restrict__ addsrc, const float* __restrict__ pos_emb,
    const int* __restrict__ pidx, float* __restrict__ out, int n)
{
    constexpr int KS = KTILE * NPASS;        // Wt row stride
    constexpr int ROWB = KTILE * 2;          // LDS row bytes
    __shared__ __align__(16) char alds[64 * KTILE * 2];
    __shared__ float red[4][64][2];

    int tid = threadIdx.x, lane = tid & 63, wv = tid >> 6;
    int cg = lane & 15, rg = lane >> 4;
    int base = blockIdx.x * 64;
    int cbase = wv * 64;

    f32x4 acc[4][4];
#pragma unroll
    for (int m = 0; m < 4; m++)
#pragma unroll
        for (int f = 0; f < 4; f++) acc[m][f] = (f32x4){0.f, 0.f, 0.f, 0.f};

    for (int pass = 0; pass < NPASS; pass++) {
        if (pass) __syncthreads();
        const float* src = pass ? in1 : in0;
        constexpr int ITERS = (64 * KTILE) / (256 * 4);
#pragma unroll
        for (int i = 0; i < ITERS; i++) {
            int idx = (i * 256 + tid) * 4;
            int row = idx / KTILE;
            int k = idx & (KTILE - 1);
            int node = base + row;
            float4 v = {0.f, 0.f, 0.f, 0.f};
            if (node < n) v = *(const float4*)(src + (size_t)node * KTILE + k);
            uint2 pp;
            pp.x = pack_bf16(v.x, v.y);
            pp.y = pack_bf16(v.z, v.w);
            int off = row * ROWB + k * 2;
            off ^= (row & 7) << 4;
            *(uint2*)(alds + off) = pp;
        }
        __syncthreads();

        const unsigned short* Wp = Wt + pass * KTILE;
#pragma unroll 2
        for (int k0 = 0; k0 < KTILE; k0 += 32) {
            b16x8 a[4], b[4];
#pragma unroll
            for (int m = 0; m < 4; m++) {
                int R = m * 16 + cg;
                int off = R * ROWB + (k0 + rg * 8) * 2;
                off ^= (R & 7) << 4;
                uint4 u = *(const uint4*)(alds + off);
                a[m] = __builtin_bit_cast(b16x8, u);
            }
#pragma unroll
            for (int f = 0; f < 4; f++) {
                const unsigned short* p = Wp + (size_t)(cbase + f * 16 + cg) * KS + k0 + rg * 8;
                uint4 u = *(const uint4*)p;
                b[f] = __builtin_bit_cast(b16x8, u);
            }
#pragma unroll
            for (int m = 0; m < 4; m++)
#pragma unroll
                for (int f = 0; f < 4; f++)
                    acc[m][f] = mfma16(a[m], b[f], acc[m][f]);
        }
    }

    float bias_v[4], g_v[4], be_v[4];
#pragma unroll
    for (int f = 0; f < 4; f++) {
        int col = cbase + f * 16 + cg;
        bias_v[f] = bias[col];
        if (RELU_LN) { g_v[f] = g[col]; be_v[f] = be[col]; }
    }
#pragma unroll
    for (int m = 0; m < 4; m++)
#pragma unroll
        for (int f = 0; f < 4; f++)
#pragma unroll
            for (int r = 0; r < 4; r++) acc[m][f][r] += bias_v[f];

    if (RELU_LN) {
#pragma unroll
        for (int m = 0; m < 4; m++)
#pragma unroll
            for (int f = 0; f < 4; f++)
#pragma unroll
                for (int r = 0; r < 4; r++) acc[m][f][r] = fmaxf(acc[m][f][r], 0.f);
#pragma unroll
        for (int m = 0; m < 4; m++)
#pragma unroll
            for (int r = 0; r < 4; r++) {
                float s = acc[m][0][r] + acc[m][1][r] + acc[m][2][r] + acc[m][3][r];
                float q = acc[m][0][r] * acc[m][0][r] + acc[m][1][r] * acc[m][1][r]
                        + acc[m][2][r] * acc[m][2][r] + acc[m][3][r] * acc[m][3][r];
#pragma unroll
                for (int o = 1; o < 16; o <<= 1) {
                    s += __shfl_xor(s, o, 64);
                    q += __shfl_xor(q, o, 64);
                }
                if (cg == 0) {
                    int R = m * 16 + rg * 4 + r;
                    red[wv][R][0] = s;
                    red[wv][R][1] = q;
                }
            }
        __syncthreads();
#pragma unroll
        for (int m = 0; m < 4; m++)
#pragma unroll
            for (int r = 0; r < 4; r++) {
                int R = m * 16 + rg * 4 + r;
                float S = red[0][R][0] + red[1][R][0] + red[2][R][0] + red[3][R][0];
                float Q = red[0][R][1] + red[1][R][1] + red[2][R][1] + red[3][R][1];
                float mu = S * (1.f / HID);
                float var = Q * (1.f / HID) - mu * mu;
                float rs = rsqrtf(var + EPSV);
#pragma unroll
                for (int f = 0; f < 4; f++)
                    acc[m][f][r] = (acc[m][f][r] - mu) * rs * g_v[f] + be_v[f];
            }
    }

#pragma unroll
    for (int m = 0; m < 4; m++)
#pragma unroll
        for (int r = 0; r < 4; r++) {
            int row = base + m * 16 + rg * 4 + r;
            if (row >= n) continue;
            size_t ro = (size_t)row * HID;
            int pid = 0;
            if (POS) pid = pidx[row];
#pragma unroll
            for (int f = 0; f < 4; f++) {
                int col = cbase + f * 16 + cg;
                float v = acc[m][f][r];
                if (ADD_RES) v += addsrc[ro + col];
                if (POS)     v += pos_emb[(size_t)pid * HID + col];
                out[ro + col] = v;
            }
        }
}

// ---------------- fused QKV MFMA: stage h once, 3 weight passes, bf16 out ----------------
__global__ __launch_bounds__(256) void qkv_mfma_kernel(
    const float* __restrict__ hsrc,
    const unsigned short* __restrict__ Wtq, const unsigned short* __restrict__ Wtk,
    const unsigned short* __restrict__ Wtv,
    const float* __restrict__ bq, const float* __restrict__ bk, const float* __restrict__ bv,
    unsigned short* __restrict__ Qo, unsigned short* __restrict__ Ko,
    unsigned short* __restrict__ Vo, int n)
{
    constexpr int ROWB = 512;                // 256 bf16 per row
    __shared__ __align__(16) char alds[64 * 512];
    int tid = threadIdx.x, lane = tid & 63, wv = tid >> 6;
    int cg = lane & 15, rg = lane >> 4;
    int base = blockIdx.x * 64;
    int cbase = wv * 64;

#pragma unroll
    for (int i = 0; i < 16; i++) {
        int idx = (i * 256 + tid) * 4;
        int row = idx >> 8;
        int k = idx & 255;
        int node = base + row;
        float4 v = {0.f, 0.f, 0.f, 0.f};
        if (node < n) v = *(const float4*)(hsrc + (size_t)node * HID + k);
        uint2 pp;
        pp.x = pack_bf16(v.x, v.y);
        pp.y = pack_bf16(v.z, v.w);
        int off = row * ROWB + k * 2;
        off ^= (row & 7) << 4;
        *(uint2*)(alds + off) = pp;
    }
    __syncthreads();

    for (int mat = 0; mat < 3; mat++) {
        const unsigned short* Wp = (mat == 0) ? Wtq : (mat == 1) ? Wtk : Wtv;
        const float* bp = (mat == 0) ? bq : (mat == 1) ? bk : bv;
        unsigned short* op = (mat == 0) ? Qo : (mat == 1) ? Ko : Vo;

        f32x4 acc[4][4];
#pragma unroll
        for (int m = 0; m < 4; m++)
#pragma unroll
            for (int f = 0; f < 4; f++) acc[m][f] = (f32x4){0.f, 0.f, 0.f, 0.f};

#pragma unroll 2
        for (int k0 = 0; k0 < 256; k0 += 32) {
            b16x8 a[4], b[4];
#pragma unroll
            for (int m = 0; m < 4; m++) {
                int R = m * 16 + cg;
                int off = R * ROWB + (k0 + rg * 8) * 2;
                off ^= (R & 7) << 4;
                uint4 u = *(const uint4*)(alds + off);
                a[m] = __builtin_bit_cast(b16x8, u);
            }
#pragma unroll
            for (int f = 0; f < 4; f++) {
                const unsigned short* p = Wp + (size_t)(cbase + f * 16 + cg) * 256 + k0 + rg * 8;
                uint4 u = *(const uint4*)p;
                b[f] = __builtin_bit_cast(b16x8, u);
            }
#pragma unroll
            for (int m = 0; m < 4; m++)
#pragma unroll
                for (int f = 0; f < 4; f++)
                    acc[m][f] = mfma16(a[m], b[f], acc[m][f]);
        }

        float bias_v[4];
#pragma unroll
        for (int f = 0; f < 4; f++) bias_v[f] = bp[cbase + f * 16 + cg];
#pragma unroll
        for (int m = 0; m < 4; m++)
#pragma unroll
            for (int r = 0; r < 4; r++) {
                int row = base + m * 16 + rg * 4 + r;
                if (row >= n) continue;
                size_t ro = (size_t)row * HID;
#pragma unroll
                for (int f = 0; f < 4; f++) {
                    int col = cbase + f * 16 + cg;
                    float v = acc[m][f][r] + bias_v[f];
                    op[ro + col] = __builtin_bit_cast(unsigned short, (__bf16)v);
                }
            }
    }
}

// ---------------- CSR build ----------------
__global__ void count_kernel(const int* __restrict__ row, int* __restrict__ counts, int e)
{
    int i = blockIdx.x * blockDim.x + threadIdx.x;
    if (i < e) atomicAdd(&counts[row[i]], 1);
}

__global__ __launch_bounds__(256) void scan1_kernel(const int* __restrict__ counts,
    int* __restrict__ offs, int* __restrict__ bsum, int n)
{
    __shared__ int wsumS[4];
    int tid = threadIdx.x, b = blockIdx.x;
    int i = b * 256 + tid;
    int v = (i < n) ? counts[i] : 0;
    int lane = tid & 63, wv = tid >> 6;
    int s = v;
#pragma unroll
    for (int o = 1; o < 64; o <<= 1) { int t = __shfl_up(s, o, 64); if (lane >= o) s += t; }
    if (lane == 63) wsumS[wv] = s;
    __syncthreads();
    int add = 0;
    for (int j = 0; j < wv; j++) add += wsumS[j];
    s += add;
    if (i < n) offs[i + 1] = s;
    if (tid == 255) bsum[b] = s;
}

__global__ __launch_bounds__(256) void scan2_kernel(int* __restrict__ bsum, int nb)
{
    __shared__ int wsumS[4];
    int tid = threadIdx.x;
    int v = (tid < nb) ? bsum[tid] : 0;
    int lane = tid & 63, wv = tid >> 6;
    int s = v;
#pragma unroll
    for (int o = 1; o < 64; o <<= 1) { int t = __shfl_up(s, o, 64); if (lane >= o) s += t; }
    if (lane == 63) wsumS[wv] = s;
    __syncthreads();
    int add = 0;
    for (int j = 0; j < wv; j++) add += wsumS[j];
    s += add;
    if (tid < nb) bsum[tid] = s;
}

__global__ __launch_bounds__(256) void scan3_kernel(int* __restrict__ offs,
    const int* __restrict__ bsum, int n)
{
    int tid = threadIdx.x, b = blockIdx.x;
    int i = b * 256 + tid;
    if (i == 0) offs[0] = 0;
    if (i < n && b > 0) offs[i + 1] += bsum[b - 1];
}

__global__ void scatter_kernel(const int* __restrict__ row, const int* __restrict__ col,
    const int* __restrict__ offs, int* __restrict__ cur, int* __restrict__ ccol, int e)
{
    int i = blockIdx.x * blockDim.x + threadIdx.x;
    if (i >= e) return;
    int r = row[i];
    int pos = atomicAdd(&cur[r], 1);
    ccol[offs[r] + pos] = col[i];
}

// ---------------- fused attention, bf16 Q/K/V gathers ----------------
// block = node; 8 half-waves; half-wave = 1 edge; lane covers 8 dims (16B loads).
__global__ __launch_bounds__(256) void attn_bf16_kernel(
    const unsigned short* __restrict__ Qm, const unsigned short* __restrict__ Km,
    const unsigned short* __restrict__ Vm,
    const int* __restrict__ offs, const int* __restrict__ ccol,
    float* __restrict__ agg, int n)
{
    __shared__ float accT[8][HID];
    __shared__ float wredM[8][HEADS];
    __shared__ float wredD[8][HEADS];
    int node = blockIdx.x;
    int tid = threadIdx.x, lane = tid & 63, wv = tid >> 6;
    int hw = (wv << 1) | (lane >> 5);     // half-wave 0..7
    int l32 = lane & 31;
    int grp = l32 >> 3;                   // head of this lane's 8 dims
    int start = offs[node], fin = offs[node + 1];
    if (fin == start) { agg[(size_t)node * HID + tid] = 0.f; return; }

    uint4 qr = *(const uint4*)(Qm + (size_t)node * HID + l32 * 8);
    float qf[8];
    unpack2(qr.x, qf[0], qf[1]);
    unpack2(qr.y, qf[2], qf[3]);
    unpack2(qr.z, qf[4], qf[5]);
    unpack2(qr.w, qf[6], qf[7]);

    float m = -3.0e38f, d = 0.f;
    float acc[8];
#pragma unroll
    for (int j = 0; j < 8; j++) acc[j] = 0.f;

    for (int i = start + hw; i < fin; i += 8) {
        int c = ccol[i];
        const unsigned short* kp = Km + (size_t)c * HID + l32 * 8;
        const unsigned short* vp = Vm + (size_t)c * HID + l32 * 8;
        uint4 kr = *(const uint4*)kp;
        float k0, k1, k2, k3, k4, k5, k6, k7;
        unpack2(kr.x, k0, k1); unpack2(kr.y, k2, k3);
        unpack2(kr.z, k4, k5); unpack2(kr.w, k6, k7);
        float p = qf[0] * k0 + qf[1] * k1 + qf[2] * k2 + qf[3] * k3
                + qf[4] * k4 + qf[5] * k5 + qf[6] * k6 + qf[7] * k7;
        p += __shfl_xor(p, 1, 64);
        p += __shfl_xor(p, 2, 64);
        p += __shfl_xor(p, 4, 64);
        float s = p * 0.125f;
        float mn = fmaxf(m, s);
        float sc = __expf(m - mn);
        float w = __expf(s - mn);
        d = d * sc + w;
        uint4 vr = *(const uint4*)vp;
        float v0, v1, v2, v3, v4, v5, v6, v7;
        unpack2(vr.x, v0, v1); unpack2(vr.y, v2, v3);
        unpack2(vr.z, v4, v5); unpack2(vr.w, v6, v7);
        acc[0] = acc[0] * sc + w * v0;  acc[1] = acc[1] * sc + w * v1;
        acc[2] = acc[2] * sc + w * v2;  acc[3] = acc[3] * sc + w * v3;
        acc[4] = acc[4] * sc + w * v4;  acc[5] = acc[5] * sc + w * v5;
        acc[6] = acc[6] * sc + w * v6;  acc[7] = acc[7] * sc + w * v7;
        m = mn;
    }
    if ((l32 & 7) == 0) { wredM[hw][grp] = m; wredD[hw][grp] = d; }
    __syncthreads();
    float M = wredM[0][grp];
#pragma unroll
    for (int j = 1; j < 8; j++) M = fmaxf(M, wredM[j][grp]);
    float fac = __expf(m - M);
    float4 a0 = {acc[0] * fac, acc[1] * fac, acc[2] * fac, acc[3] * fac};
    float4 a1 = {acc[4] * fac, acc[5] * fac, acc[6] * fac, acc[7] * fac};
    *(float4*)&accT[hw][l32 * 8]     = a0;
    *(float4*)&accT[hw][l32 * 8 + 4] = a1;
    __syncthreads();
    int hh = tid >> 6;
    float M2 = wredM[0][hh];
#pragma unroll
    for (int j = 1; j < 8; j++) M2 = fmaxf(M2, wredM[j][hh]);
    float D = 0.f;
#pragma unroll
    for (int j = 0; j < 8; j++) D += wredD[j][hh] * __expf(wredM[j][hh] - M2);
    float r = 0.f;
#pragma unroll
    for (int j = 0; j < 8; j++) r += accT[j][tid];
    agg[(size_t)node * HID + tid] = r / D;
}

// ---------------- pooling ----------------
__global__ void bounds_kernel(const int* __restrict__ batch, int* __restrict__ gb, int n)
{
    int g = threadIdx.x;
    if (g > GRAPHS) return;
    int lo = 0, hi = n;
    while (lo < hi) { int mid = (lo + hi) >> 1; if (batch[mid] < g) lo = mid + 1; else hi = mid; }
    gb[g] = lo;
}

__global__ __launch_bounds__(256) void pool_kernel(const float* __restrict__ h,
    const int* __restrict__ gb, float* __restrict__ pooled)
{
    int g = blockIdx.x, tid = threadIdx.x;
    int s = gb[g], e = gb[g + 1];
    float sum = 0.f;
    for (int i = s; i < e; i++) sum += h[(size_t)i * HID + tid];
    pooled[g * HID + tid] = sum / fmaxf((float)(e - s), 1.f);
}

// ---------------- classifier ----------------
__global__ __launch_bounds__(256) void cls_kernel(const float* __restrict__ pooled,
    const float* __restrict__ W1, const float* __restrict__ b1,
    const float* __restrict__ g, const float* __restrict__ be,
    const float* __restrict__ W2, const float* __restrict__ b2,
    float* __restrict__ out)
{
    __shared__ float pin[HID];
    __shared__ float hbuf[HID];
    __shared__ float red2[4][2];
    int tid = threadIdx.x, gi = blockIdx.x;
    int lane = tid & 63, wv = tid >> 6;
    pin[tid] = pooled[gi * HID + tid];
    __syncthreads();
    float acc = 0.f;
    for (int k = 0; k < HID; k++) acc += pin[k] * W1[k * HID + tid];
    acc = fmaxf(acc + b1[tid], 0.f);
    float s = acc, q = acc * acc;
#pragma unroll
    for (int o = 1; o < 64; o <<= 1) { s += __shfl_xor(s, o, 64); q += __shfl_xor(q, o, 64); }
    if (lane == 0) { red2[wv][0] = s; red2[wv][1] = q; }
    __syncthreads();
    float S = red2[0][0] + red2[1][0] + red2[2][0] + red2[3][0];
    float Q = red2[0][1] + red2[1][1] + red2[2][1] + red2[3][1];
    float mu = S * (1.f / HID);
    float rs = rsqrtf(Q * (1.f / HID) - mu * mu + EPSV);
    hbuf[tid] = (acc - mu) * rs * g[tid] + be[tid];
    __syncthreads();
    if (tid < OUTC) {
        float o = 0.f;
        for (int k = 0; k < HID; k++) o += hbuf[k] * W2[k * OUTC + tid];
        out[gi * OUTC + tid] = o + b2[tid];
    }
}

// ---------------- host launch ----------------
extern "C" void kernel_launch(void* const* d_in, const int* in_sizes, int n_in,
                              void* d_out, int out_size, void* d_ws, size_t ws_size,
                              hipStream_t stream)
{
    const float* x        = (const float*)d_in[0];
    const int*   ei       = (const int*)d_in[1];
    const int*   pidx     = (const int*)d_in[2];
    const int*   batch    = (const int*)d_in[3];
    const float* enc_w1   = (const float*)d_in[4];
    const float* enc_b1   = (const float*)d_in[5];
    const float* enc_g    = (const float*)d_in[6];
    const float* enc_beta = (const float*)d_in[7];
    const float* enc_w2   = (const float*)d_in[8];
    const float* enc_b2   = (const float*)d_in[9];
    const float* pos_emb  = (const float*)d_in[10];
    const float* Wq       = (const float*)d_in[11];
    const float* bq       = (const float*)d_in[12];
    const float* Wk       = (const float*)d_in[13];
    const float* bk       = (const float*)d_in[14];
    const float* Wv       = (const float*)d_in[15];
    const float* bv       = (const float*)d_in[16];
    const float* mlp_w1   = (const float*)d_in[17];
    const float* mlp_b1   = (const float*)d_in[18];
    const float* mlp_g    = (const float*)d_in[19];
    const float* mlp_beta = (const float*)d_in[20];
    const float* mlp_w2   = (const float*)d_in[21];
    const float* mlp_b2   = (const float*)d_in[22];
    const float* cls_w1   = (const float*)d_in[23];
    const float* cls_b1   = (const float*)d_in[24];
    const float* cls_g    = (const float*)d_in[25];
    const float* cls_beta = (const float*)d_in[26];
    const float* cls_w2   = (const float*)d_in[27];
    const float* cls_b2   = (const float*)d_in[28];

    int n = in_sizes[2];            // 50000
    int e = in_sizes[1] / 2;        // 800000
    const int* row = ei;
    const int* col = ei + e;

    char* p = (char*)d_ws;
    auto alloc = [&](size_t bytes) -> void* {
        void* r = (void*)p;
        p += (bytes + 255) & ~(size_t)255;
        return r;
    };
    size_t NH = (size_t)n * HID;
    float* h   = (float*)alloc(NH * 4);
    float* t   = (float*)alloc(NH * 4);   // enc hidden / agg / mlp hidden
    unsigned short* Qb = (unsigned short*)alloc(NH * 2);
    unsigned short* Kb = (unsigned short*)alloc(NH * 2);
    unsigned short* Vb = (unsigned short*)alloc(NH * 2);
    float* pooled = (float*)alloc(GRAPHS * HID * 4);
    int* counts = (int*)alloc((size_t)n * 4);
    int* offs   = (int*)alloc((size_t)(n + 1) * 4);
    int* cur    = (int*)alloc((size_t)n * 4);
    int* ccol   = (int*)alloc((size_t)e * 4);
    int* bsum   = (int*)alloc(1024);
    int* gb     = (int*)alloc((GRAPHS + 1) * 4);
    unsigned short* wt_e1 = (unsigned short*)alloc((size_t)128 * 256 * 2);
    unsigned short* wt_e2 = (unsigned short*)alloc((size_t)256 * 256 * 2);
    unsigned short* wt_q  = (unsigned short*)alloc((size_t)4 * 256 * 256 * 2);
    unsigned short* wt_k  = (unsigned short*)alloc((size_t)4 * 256 * 256 * 2);
    unsigned short* wt_v  = (unsigned short*)alloc((size_t)4 * 256 * 256 * 2);
    unsigned short* wt_m1 = (unsigned short*)alloc((size_t)4 * 512 * 256 * 2);
    unsigned short* wt_m2 = (unsigned short*)alloc((size_t)4 * 256 * 256 * 2);

    int gblocks = (n + 63) / 64;
    int nb = (n + 255) / 256;

    // ---- weight prep ----
    wtrans_kernel<<<dim3(4, 8, 1),  256, 0, stream>>>(enc_w1, wt_e1, 128, 256);
    wtrans_kernel<<<dim3(8, 8, 1),  256, 0, stream>>>(enc_w2, wt_e2, 256, 256);
    wtrans_kernel<<<dim3(8, 8, 4),  256, 0, stream>>>(Wq,     wt_q,  256, 256);
    wtrans_kernel<<<dim3(8, 8, 4),  256, 0, stream>>>(Wk,     wt_k,  256, 256);
    wtrans_kernel<<<dim3(8, 8, 4),  256, 0, stream>>>(Wv,     wt_v,  256, 256);
    wtrans_kernel<<<dim3(16, 8, 4), 256, 0, stream>>>(mlp_w1, wt_m1, 512, 256);
    wtrans_kernel<<<dim3(8, 8, 4),  256, 0, stream>>>(mlp_w2, wt_m2, 256, 256);

    // ---- CSR build ----
    hipMemsetAsync(counts, 0, (size_t)n * 4, stream);
    hipMemsetAsync(cur, 0, (size_t)n * 4, stream);
    count_kernel<<<(e + 255) / 256, 256, 0, stream>>>(row, counts, e);
    scan1_kernel<<<nb, 256, 0, stream>>>(counts, offs, bsum, n);
    scan2_kernel<<<1, 256, 0, stream>>>(bsum, nb);
    scan3_kernel<<<nb, 256, 0, stream>>>(offs, bsum, n);
    scatter_kernel<<<(e + 255) / 256, 256, 0, stream>>>(row, col, offs, cur, ccol, e);

    // ---- encoder ----
    gemm_mfma<128, 1, true, false, false><<<gblocks, 256, 0, stream>>>(
        x, nullptr, wt_e1, enc_b1, enc_g, enc_beta, nullptr, nullptr, nullptr, t, n);
    gemm_mfma<256, 1, false, false, true><<<gblocks, 256, 0, stream>>>(
        t, nullptr, wt_e2, enc_b2, nullptr, nullptr, nullptr, pos_emb, pidx, h, n);

    // ---- attention layers ----
    for (int l = 0; l < 4; l++) {
        size_t wo = (size_t)l * 256 * 256;
        size_t bo = (size_t)l * HID;
        qkv_mfma_kernel<<<gblocks, 256, 0, stream>>>(
            h, wt_q + wo, wt_k + wo, wt_v + wo, bq + bo, bk + bo, bv + bo,
            Qb, Kb, Vb, n);
        attn_bf16_kernel<<<n, 256, 0, stream>>>(Qb, Kb, Vb, offs, ccol, t, n);
        gemm_mfma<256, 2, true, false, false><<<gblocks, 256, 0, stream>>>(
            h, t, wt_m1 + (size_t)l * 512 * 256, mlp_b1 + bo,
            mlp_g + bo, mlp_beta + bo, nullptr, nullptr, nullptr, t, n);
        gemm_mfma<256, 1, false, true, false><<<gblocks, 256, 0, stream>>>(
            t, nullptr, wt_m2 + wo, mlp_b2 + bo, nullptr, nullptr, h, nullptr, nullptr, h, n);
    }

    // ---- pool + classifier ----
    bounds_kernel<<<1, 128, 0, stream>>>(batch, gb, n);
    pool_kernel<<<GRAPHS, 256, 0, stream>>>(h, gb, pooled);
    cls_kernel<<<GRAPHS, 256, 0, stream>>>(pooled, cls_w1, cls_b1, cls_g, cls_beta,
                                           cls_w2, cls_b2, (float*)d_out);
}

// Round 4
// 1419.394 us; speedup vs baseline: 3.4545x; 1.2079x over previous
//
#include <hip/hip_runtime.h>
#include <cstdint>

#define HID 256
#define HEADS 4
#define GRAPHS 64
#define OUTC 32
#define EPSV 1e-5f
#define PSPLIT 32

typedef __bf16 b16x8 __attribute__((ext_vector_type(8)));
typedef float  f32x4 __attribute__((ext_vector_type(4)));

__device__ __forceinline__ f32x4 mfma16(b16x8 a, b16x8 b, f32x4 c) {
    return __builtin_amdgcn_mfma_f32_16x16x32_bf16(a, b, c, 0, 0, 0);
}

__device__ __forceinline__ unsigned int pack_bf16(float a, float b) {
    unsigned short ua = __builtin_bit_cast(unsigned short, (__bf16)a);
    unsigned short ub = __builtin_bit_cast(unsigned short, (__bf16)b);
    return (unsigned int)ua | ((unsigned int)ub << 16);
}

__device__ __forceinline__ void unpack2(unsigned int u, float& lo, float& hi) {
    lo = __builtin_bit_cast(float, u << 16);
    hi = __builtin_bit_cast(float, u & 0xffff0000u);
}

// ---------------- weight transpose + bf16 convert: W[K][C] -> Wt[C][K] ----------------
__global__ __launch_bounds__(256) void wtrans_kernel(const float* __restrict__ W,
    unsigned short* __restrict__ Wt, int K, int C)
{
    __shared__ float tile[32][33];
    const float* Wm = W + (size_t)blockIdx.z * K * C;
    unsigned short* Wtm = Wt + (size_t)blockIdx.z * K * C;
    int k0 = blockIdx.x * 32, c0 = blockIdx.y * 32;
    int tx = threadIdx.x & 31, ty = threadIdx.x >> 5;
#pragma unroll
    for (int i = 0; i < 32; i += 8)
        tile[ty + i][tx] = Wm[(size_t)(k0 + ty + i) * C + c0 + tx];
    __syncthreads();
#pragma unroll
    for (int i = 0; i < 32; i += 8) {
        float v = tile[tx][ty + i];
        Wtm[(size_t)(c0 + ty + i) * K + k0 + tx] =
            __builtin_bit_cast(unsigned short, (__bf16)v);
    }
}

// ---------------- enc1: fp32 in (x, K=128), bf16 out, ReLU+LN ----------------
__global__ __launch_bounds__(256) void enc1_mfma(
    const float* __restrict__ in0, const unsigned short* __restrict__ Wt,
    const float* __restrict__ bias, const float* __restrict__ g,
    const float* __restrict__ be, unsigned short* __restrict__ outb, int n)
{
    constexpr int KTILE = 128, ROWB = 256;
    __shared__ __align__(16) char alds[64 * 256];
    __shared__ float red[4][64][2];
    int tid = threadIdx.x, lane = tid & 63, wv = tid >> 6;
    int cg = lane & 15, rg = lane >> 4;
    int base = blockIdx.x * 64;
    int cbase = wv * 64;

    f32x4 acc[4][4];
#pragma unroll
    for (int m = 0; m < 4; m++)
#pragma unroll
        for (int f = 0; f < 4; f++) acc[m][f] = (f32x4){0.f, 0.f, 0.f, 0.f};

#pragma unroll
    for (int i = 0; i < 8; i++) {
        int idx = (i * 256 + tid) * 4;
        int row = idx >> 7, k = idx & 127;
        int node = base + row;
        float4 v = {0.f, 0.f, 0.f, 0.f};
        if (node < n) v = *(const float4*)(in0 + (size_t)node * KTILE + k);
        uint2 pp; pp.x = pack_bf16(v.x, v.y); pp.y = pack_bf16(v.z, v.w);
        int off = row * ROWB + k * 2;
        off ^= (row & 7) << 4;
        *(uint2*)(alds + off) = pp;
    }
    __syncthreads();

#pragma unroll 2
    for (int k0 = 0; k0 < KTILE; k0 += 32) {
        b16x8 a[4], b[4];
#pragma unroll
        for (int m = 0; m < 4; m++) {
            int R = m * 16 + cg;
            int off = R * ROWB + (k0 + rg * 8) * 2;
            off ^= (R & 7) << 4;
            a[m] = __builtin_bit_cast(b16x8, *(const uint4*)(alds + off));
        }
#pragma unroll
        for (int f = 0; f < 4; f++) {
            const unsigned short* p = Wt + (size_t)(cbase + f * 16 + cg) * KTILE + k0 + rg * 8;
            b[f] = __builtin_bit_cast(b16x8, *(const uint4*)p);
        }
#pragma unroll
        for (int m = 0; m < 4; m++)
#pragma unroll
            for (int f = 0; f < 4; f++)
                acc[m][f] = mfma16(a[m], b[f], acc[m][f]);
    }

    float bias_v[4], g_v[4], be_v[4];
#pragma unroll
    for (int f = 0; f < 4; f++) {
        int col = cbase + f * 16 + cg;
        bias_v[f] = bias[col]; g_v[f] = g[col]; be_v[f] = be[col];
    }
#pragma unroll
    for (int m = 0; m < 4; m++)
#pragma unroll
        for (int f = 0; f < 4; f++)
#pragma unroll
            for (int r = 0; r < 4; r++)
                acc[m][f][r] = fmaxf(acc[m][f][r] + bias_v[f], 0.f);
#pragma unroll
    for (int m = 0; m < 4; m++)
#pragma unroll
        for (int r = 0; r < 4; r++) {
            float s = acc[m][0][r] + acc[m][1][r] + acc[m][2][r] + acc[m][3][r];
            float q = acc[m][0][r] * acc[m][0][r] + acc[m][1][r] * acc[m][1][r]
                    + acc[m][2][r] * acc[m][2][r] + acc[m][3][r] * acc[m][3][r];
#pragma unroll
            for (int o = 1; o < 16; o <<= 1) {
                s += __shfl_xor(s, o, 64); q += __shfl_xor(q, o, 64);
            }
            if (cg == 0) { int R = m * 16 + rg * 4 + r; red[wv][R][0] = s; red[wv][R][1] = q; }
        }
    __syncthreads();
#pragma unroll
    for (int m = 0; m < 4; m++)
#pragma unroll
        for (int r = 0; r < 4; r++) {
            int R = m * 16 + rg * 4 + r;
            float S = red[0][R][0] + red[1][R][0] + red[2][R][0] + red[3][R][0];
            float Q = red[0][R][1] + red[1][R][1] + red[2][R][1] + red[3][R][1];
            float mu = S * (1.f / HID);
            float rs = rsqrtf(Q * (1.f / HID) - mu * mu + EPSV);
            int row = base + R;
            if (row >= n) continue;
            size_t ro = (size_t)row * HID;
#pragma unroll
            for (int f = 0; f < 4; f++) {
                float v = (acc[m][f][r] - mu) * rs * g_v[f] + be_v[f];
                outb[ro + cbase + f * 16 + cg] = __builtin_bit_cast(unsigned short, (__bf16)v);
            }
        }
}

// ---------------- generic MFMA GEMM, bf16 inputs ----------------
template<int KTILE, int NPASS, bool RELU_LN, bool ADD_RES, bool POS, bool OUTF, bool OUTB>
__global__ __launch_bounds__(256) void gemm_bf16(
    const unsigned short* __restrict__ in0, const unsigned short* __restrict__ in1,
    const unsigned short* __restrict__ Wt, const float* __restrict__ bias,
    const float* __restrict__ g, const float* __restrict__ be,
    const float* __restrict__ addsrc, const float* __restrict__ pos_emb,
    const int* __restrict__ pidx, float* __restrict__ outf,
    unsigned short* __restrict__ outb, int n)
{
    constexpr int KS = KTILE * NPASS;
    constexpr int ROWB = KTILE * 2;
    constexpr int UPR = KTILE / 8;           // 16B units per row
    __shared__ __align__(16) char alds[64 * KTILE * 2];
    __shared__ float red[4][64][2];

    int tid = threadIdx.x, lane = tid & 63, wv = tid >> 6;
    int cg = lane & 15, rg = lane >> 4;
    int base = blockIdx.x * 64;
    int cbase = wv * 64;

    f32x4 acc[4][4];
#pragma unroll
    for (int m = 0; m < 4; m++)
#pragma unroll
        for (int f = 0; f < 4; f++) acc[m][f] = (f32x4){0.f, 0.f, 0.f, 0.f};

    for (int pass = 0; pass < NPASS; pass++) {
        if (pass) __syncthreads();
        const unsigned short* src = pass ? in1 : in0;
        constexpr int ITERS = (64 * UPR) / 256;
#pragma unroll
        for (int i = 0; i < ITERS; i++) {
            int idx = i * 256 + tid;
            int row = idx / UPR, u = idx % UPR;
            int node = base + row;
            uint4 v = {0u, 0u, 0u, 0u};
            if (node < n) v = *(const uint4*)(src + (size_t)node * KTILE + u * 8);
            int off = row * ROWB + u * 16;
            off ^= (row & 7) << 4;
            *(uint4*)(alds + off) = v;
        }
        __syncthreads();

        const unsigned short* Wp = Wt + pass * KTILE;
#pragma unroll 2
        for (int k0 = 0; k0 < KTILE; k0 += 32) {
            b16x8 a[4], b[4];
#pragma unroll
            for (int m = 0; m < 4; m++) {
                int R = m * 16 + cg;
                int off = R * ROWB + (k0 + rg * 8) * 2;
                off ^= (R & 7) << 4;
                a[m] = __builtin_bit_cast(b16x8, *(const uint4*)(alds + off));
            }
#pragma unroll
            for (int f = 0; f < 4; f++) {
                const unsigned short* p = Wp + (size_t)(cbase + f * 16 + cg) * KS + k0 + rg * 8;
                b[f] = __builtin_bit_cast(b16x8, *(const uint4*)p);
            }
#pragma unroll
            for (int m = 0; m < 4; m++)
#pragma unroll
                for (int f = 0; f < 4; f++)
                    acc[m][f] = mfma16(a[m], b[f], acc[m][f]);
        }
    }

    float bias_v[4], g_v[4], be_v[4];
#pragma unroll
    for (int f = 0; f < 4; f++) {
        int col = cbase + f * 16 + cg;
        bias_v[f] = bias[col];
        if (RELU_LN) { g_v[f] = g[col]; be_v[f] = be[col]; }
    }
#pragma unroll
    for (int m = 0; m < 4; m++)
#pragma unroll
        for (int f = 0; f < 4; f++)
#pragma unroll
            for (int r = 0; r < 4; r++) acc[m][f][r] += bias_v[f];

    if (RELU_LN) {
#pragma unroll
        for (int m = 0; m < 4; m++)
#pragma unroll
            for (int f = 0; f < 4; f++)
#pragma unroll
                for (int r = 0; r < 4; r++) acc[m][f][r] = fmaxf(acc[m][f][r], 0.f);
#pragma unroll
        for (int m = 0; m < 4; m++)
#pragma unroll
            for (int r = 0; r < 4; r++) {
                float s = acc[m][0][r] + acc[m][1][r] + acc[m][2][r] + acc[m][3][r];
                float q = acc[m][0][r] * acc[m][0][r] + acc[m][1][r] * acc[m][1][r]
                        + acc[m][2][r] * acc[m][2][r] + acc[m][3][r] * acc[m][3][r];
#pragma unroll
                for (int o = 1; o < 16; o <<= 1) {
                    s += __shfl_xor(s, o, 64); q += __shfl_xor(q, o, 64);
                }
                if (cg == 0) { int R = m * 16 + rg * 4 + r; red[wv][R][0] = s; red[wv][R][1] = q; }
            }
        __syncthreads();
#pragma unroll
        for (int m = 0; m < 4; m++)
#pragma unroll
            for (int r = 0; r < 4; r++) {
                int R = m * 16 + rg * 4 + r;
                float S = red[0][R][0] + red[1][R][0] + red[2][R][0] + red[3][R][0];
                float Q = red[0][R][1] + red[1][R][1] + red[2][R][1] + red[3][R][1];
                float mu = S * (1.f / HID);
                float rs = rsqrtf(Q * (1.f / HID) - mu * mu + EPSV);
#pragma unroll
                for (int f = 0; f < 4; f++)
                    acc[m][f][r] = (acc[m][f][r] - mu) * rs * g_v[f] + be_v[f];
            }
    }

#pragma unroll
    for (int m = 0; m < 4; m++)
#pragma unroll
        for (int r = 0; r < 4; r++) {
            int row = base + m * 16 + rg * 4 + r;
            if (row >= n) continue;
            size_t ro = (size_t)row * HID;
            int pid = 0;
            if (POS) pid = pidx[row];
#pragma unroll
            for (int f = 0; f < 4; f++) {
                int col = cbase + f * 16 + cg;
                float v = acc[m][f][r];
                if (ADD_RES) v += addsrc[ro + col];
                if (POS)     v += pos_emb[(size_t)pid * HID + col];
                if (OUTF)    outf[ro + col] = v;
                if (OUTB)    outb[ro + col] = __builtin_bit_cast(unsigned short, (__bf16)v);
            }
        }
}

// ---------------- fused QKV MFMA: bf16 h in, 3 weight passes, bf16 out ----------------
__global__ __launch_bounds__(256) void qkv_mfma_kernel(
    const unsigned short* __restrict__ hsrc,
    const unsigned short* __restrict__ Wtq, const unsigned short* __restrict__ Wtk,
    const unsigned short* __restrict__ Wtv,
    const float* __restrict__ bq, const float* __restrict__ bk, const float* __restrict__ bv,
    unsigned short* __restrict__ Qo, unsigned short* __restrict__ Ko,
    unsigned short* __restrict__ Vo, int n)
{
    constexpr int ROWB = 512;
    __shared__ __align__(16) char alds[64 * 512];
    int tid = threadIdx.x, lane = tid & 63, wv = tid >> 6;
    int cg = lane & 15, rg = lane >> 4;
    int base = blockIdx.x * 64;
    int cbase = wv * 64;

#pragma unroll
    for (int i = 0; i < 8; i++) {
        int idx = i * 256 + tid;
        int row = idx >> 5, u = idx & 31;
        int node = base + row;
        uint4 v = {0u, 0u, 0u, 0u};
        if (node < n) v = *(const uint4*)(hsrc + (size_t)node * HID + u * 8);
        int off = row * ROWB + u * 16;
        off ^= (row & 7) << 4;
        *(uint4*)(alds + off) = v;
    }
    __syncthreads();

    for (int mat = 0; mat < 3; mat++) {
        const unsigned short* Wp = (mat == 0) ? Wtq : (mat == 1) ? Wtk : Wtv;
        const float* bp = (mat == 0) ? bq : (mat == 1) ? bk : bv;
        unsigned short* op = (mat == 0) ? Qo : (mat == 1) ? Ko : Vo;

        f32x4 acc[4][4];
#pragma unroll
        for (int m = 0; m < 4; m++)
#pragma unroll
            for (int f = 0; f < 4; f++) acc[m][f] = (f32x4){0.f, 0.f, 0.f, 0.f};

#pragma unroll 2
        for (int k0 = 0; k0 < 256; k0 += 32) {
            b16x8 a[4], b[4];
#pragma unroll
            for (int m = 0; m < 4; m++) {
                int R = m * 16 + cg;
                int off = R * ROWB + (k0 + rg * 8) * 2;
                off ^= (R & 7) << 4;
                a[m] = __builtin_bit_cast(b16x8, *(const uint4*)(alds + off));
            }
#pragma unroll
            for (int f = 0; f < 4; f++) {
                const unsigned short* p = Wp + (size_t)(cbase + f * 16 + cg) * 256 + k0 + rg * 8;
                b[f] = __builtin_bit_cast(b16x8, *(const uint4*)p);
            }
#pragma unroll
            for (int m = 0; m < 4; m++)
#pragma unroll
                for (int f = 0; f < 4; f++)
                    acc[m][f] = mfma16(a[m], b[f], acc[m][f]);
        }

        float bias_v[4];
#pragma unroll
        for (int f = 0; f < 4; f++) bias_v[f] = bp[cbase + f * 16 + cg];
#pragma unroll
        for (int m = 0; m < 4; m++)
#pragma unroll
            for (int r = 0; r < 4; r++) {
                int row = base + m * 16 + rg * 4 + r;
                if (row >= n) continue;
                size_t ro = (size_t)row * HID;
#pragma unroll
                for (int f = 0; f < 4; f++) {
                    float v = acc[m][f][r] + bias_v[f];
                    op[ro + cbase + f * 16 + cg] = __builtin_bit_cast(unsigned short, (__bf16)v);
                }
            }
    }
}

// ---------------- CSR build ----------------
__global__ void count_kernel(const int* __restrict__ row, int* __restrict__ counts, int e)
{
    int i = blockIdx.x * blockDim.x + threadIdx.x;
    if (i < e) atomicAdd(&counts[row[i]], 1);
}

__global__ __launch_bounds__(256) void scan1_kernel(const int* __restrict__ counts,
    int* __restrict__ offs, int* __restrict__ bsum, int n)
{
    __shared__ int wsumS[4];
    int tid = threadIdx.x, b = blockIdx.x;
    int i = b * 256 + tid;
    int v = (i < n) ? counts[i] : 0;
    int lane = tid & 63, wv = tid >> 6;
    int s = v;
#pragma unroll
    for (int o = 1; o < 64; o <<= 1) { int t = __shfl_up(s, o, 64); if (lane >= o) s += t; }
    if (lane == 63) wsumS[wv] = s;
    __syncthreads();
    int add = 0;
    for (int j = 0; j < wv; j++) add += wsumS[j];
    s += add;
    if (i < n) offs[i + 1] = s;
    if (tid == 255) bsum[b] = s;
}

__global__ __launch_bounds__(256) void scan2_kernel(int* __restrict__ bsum, int nb)
{
    __shared__ int wsumS[4];
    int tid = threadIdx.x;
    int v = (tid < nb) ? bsum[tid] : 0;
    int lane = tid & 63, wv = tid >> 6;
    int s = v;
#pragma unroll
    for (int o = 1; o < 64; o <<= 1) { int t = __shfl_up(s, o, 64); if (lane >= o) s += t; }
    if (lane == 63) wsumS[wv] = s;
    __syncthreads();
    int add = 0;
    for (int j = 0; j < wv; j++) add += wsumS[j];
    s += add;
    if (tid < nb) bsum[tid] = s;
}

__global__ __launch_bounds__(256) void scan3_kernel(int* __restrict__ offs,
    const int* __restrict__ bsum, int n)
{
    int tid = threadIdx.x, b = blockIdx.x;
    int i = b * 256 + tid;
    if (i == 0) offs[0] = 0;
    if (i < n && b > 0) offs[i + 1] += bsum[b - 1];
}

__global__ void scatter_kernel(const int* __restrict__ row, const int* __restrict__ col,
    const int* __restrict__ offs, int* __restrict__ cur, int* __restrict__ ccol, int e)
{
    int i = blockIdx.x * blockDim.x + threadIdx.x;
    if (i >= e) return;
    int r = row[i];
    int pos = atomicAdd(&cur[r], 1);
    ccol[offs[r] + pos] = col[i];
}

// ---------------- fused attention, bf16 Q/K/V gathers, bf16 agg out ----------------
__global__ __launch_bounds__(256) void attn_bf16_kernel(
    const unsigned short* __restrict__ Qm, const unsigned short* __restrict__ Km,
    const unsigned short* __restrict__ Vm,
    const int* __restrict__ offs, const int* __restrict__ ccol,
    unsigned short* __restrict__ agg, int n)
{
    __shared__ float accT[8][HID];
    __shared__ float wredM[8][HEADS];
    __shared__ float wredD[8][HEADS];
    int node = blockIdx.x;
    int tid = threadIdx.x, lane = tid & 63, wv = tid >> 6;
    int hw = (wv << 1) | (lane >> 5);
    int l32 = lane & 31;
    int grp = l32 >> 3;
    int start = offs[node], fin = offs[node + 1];
    if (fin == start) {
        agg[(size_t)node * HID + tid] = 0;
        return;
    }

    uint4 qr = *(const uint4*)(Qm + (size_t)node * HID + l32 * 8);
    float qf[8];
    unpack2(qr.x, qf[0], qf[1]);
    unpack2(qr.y, qf[2], qf[3]);
    unpack2(qr.z, qf[4], qf[5]);
    unpack2(qr.w, qf[6], qf[7]);

    float m = -3.0e38f, d = 0.f;
    float acc[8];
#pragma unroll
    for (int j = 0; j < 8; j++) acc[j] = 0.f;

    for (int i = start + hw; i < fin; i += 8) {
        int c = ccol[i];
        uint4 kr = *(const uint4*)(Km + (size_t)c * HID + l32 * 8);
        float k0, k1, k2, k3, k4, k5, k6, k7;
        unpack2(kr.x, k0, k1); unpack2(kr.y, k2, k3);
        unpack2(kr.z, k4, k5); unpack2(kr.w, k6, k7);
        float p = qf[0] * k0 + qf[1] * k1 + qf[2] * k2 + qf[3] * k3
                + qf[4] * k4 + qf[5] * k5 + qf[6] * k6 + qf[7] * k7;
        p += __shfl_xor(p, 1, 64);
        p += __shfl_xor(p, 2, 64);
        p += __shfl_xor(p, 4, 64);
        float s = p * 0.125f;
        float mn = fmaxf(m, s);
        float sc = __expf(m - mn);
        float w = __expf(s - mn);
        d = d * sc + w;
        uint4 vr = *(const uint4*)(Vm + (size_t)c * HID + l32 * 8);
        float v0, v1, v2, v3, v4, v5, v6, v7;
        unpack2(vr.x, v0, v1); unpack2(vr.y, v2, v3);
        unpack2(vr.z, v4, v5); unpack2(vr.w, v6, v7);
        acc[0] = acc[0] * sc + w * v0;  acc[1] = acc[1] * sc + w * v1;
        acc[2] = acc[2] * sc + w * v2;  acc[3] = acc[3] * sc + w * v3;
        acc[4] = acc[4] * sc + w * v4;  acc[5] = acc[5] * sc + w * v5;
        acc[6] = acc[6] * sc + w * v6;  acc[7] = acc[7] * sc + w * v7;
        m = mn;
    }
    if ((l32 & 7) == 0) { wredM[hw][grp] = m; wredD[hw][grp] = d; }
    __syncthreads();
    float M = wredM[0][grp];
#pragma unroll
    for (int j = 1; j < 8; j++) M = fmaxf(M, wredM[j][grp]);
    float fac = __expf(m - M);
    float4 a0 = {acc[0] * fac, acc[1] * fac, acc[2] * fac, acc[3] * fac};
    float4 a1 = {acc[4] * fac, acc[5] * fac, acc[6] * fac, acc[7] * fac};
    *(float4*)&accT[hw][l32 * 8]     = a0;
    *(float4*)&accT[hw][l32 * 8 + 4] = a1;
    __syncthreads();
    int hh = tid >> 6;
    float M2 = wredM[0][hh];
#pragma unroll
    for (int j = 1; j < 8; j++) M2 = fmaxf(M2, wredM[j][hh]);
    float D = 0.f;
#pragma unroll
    for (int j = 0; j < 8; j++) D += wredD[j][hh] * __expf(wredM[j][hh] - M2);
    float r = 0.f;
#pragma unroll
    for (int j = 0; j < 8; j++) r += accT[j][tid];
    agg[(size_t)node * HID + tid] = __builtin_bit_cast(unsigned short, (__bf16)(r / D));
}

// ---------------- pooling (two-stage parallel) ----------------
__global__ void bounds_kernel(const int* __restrict__ batch, int* __restrict__ gb, int n)
{
    int g = threadIdx.x;
    if (g > GRAPHS) return;
    int lo = 0, hi = n;
    while (lo < hi) { int mid = (lo + hi) >> 1; if (batch[mid] < g) lo = mid + 1; else hi = mid; }
    gb[g] = lo;
}

__global__ __launch_bounds__(256) void pool_partial_kernel(const float* __restrict__ h,
    const int* __restrict__ gb, float* __restrict__ partial)
{
    int s = blockIdx.x, g = blockIdx.y, tid = threadIdx.x;
    int lo = gb[g], hi = gb[g + 1];
    float sum = 0.f;
    for (int i = lo + s; i < hi; i += PSPLIT) sum += h[(size_t)i * HID + tid];
    partial[((size_t)g * PSPLIT + s) * HID + tid] = sum;
}

__global__ __launch_bounds__(256) void pool_reduce_kernel(const float* __restrict__ partial,
    const int* __restrict__ gb, float* __restrict__ pooled)
{
    int g = blockIdx.x, tid = threadIdx.x;
    float sum = 0.f;
#pragma unroll
    for (int s = 0; s < PSPLIT; s++) sum += partial[((size_t)g * PSPLIT + s) * HID + tid];
    int cnt = gb[g + 1] - gb[g];
    pooled[g * HID + tid] = sum / fmaxf((float)cnt, 1.f);
}

// ---------------- classifier ----------------
__global__ __launch_bounds__(256) void cls_kernel(const float* __restrict__ pooled,
    const float* __restrict__ W1, const float* __restrict__ b1,
    const float* __restrict__ g, const float* __restrict__ be,
    const float* __restrict__ W2, const float* __restrict__ b2,
    float* __restrict__ out)
{
    __shared__ float pin[HID];
    __shared__ float hbuf[HID];
    __shared__ float red2[4][2];
    int tid = threadIdx.x, gi = blockIdx.x;
    int lane = tid & 63, wv = tid >> 6;
    pin[tid] = pooled[gi * HID + tid];
    __syncthreads();
    float acc = 0.f;
    for (int k = 0; k < HID; k++) acc += pin[k] * W1[k * HID + tid];
    acc = fmaxf(acc + b1[tid], 0.f);
    float s = acc, q = acc * acc;
#pragma unroll
    for (int o = 1; o < 64; o <<= 1) { s += __shfl_xor(s, o, 64); q += __shfl_xor(q, o, 64); }
    if (lane == 0) { red2[wv][0] = s; red2[wv][1] = q; }
    __syncthreads();
    float S = red2[0][0] + red2[1][0] + red2[2][0] + red2[3][0];
    float Q = red2[0][1] + red2[1][1] + red2[2][1] + red2[3][1];
    float mu = S * (1.f / HID);
    float rs = rsqrtf(Q * (1.f / HID) - mu * mu + EPSV);
    hbuf[tid] = (acc - mu) * rs * g[tid] + be[tid];
    __syncthreads();
    if (tid < OUTC) {
        float o = 0.f;
        for (int k = 0; k < HID; k++) o += hbuf[k] * W2[k * OUTC + tid];
        out[gi * OUTC + tid] = o + b2[tid];
    }
}

// ---------------- host launch ----------------
extern "C" void kernel_launch(void* const* d_in, const int* in_sizes, int n_in,
                              void* d_out, int out_size, void* d_ws, size_t ws_size,
                              hipStream_t stream)
{
    const float* x        = (const float*)d_in[0];
    const int*   ei       = (const int*)d_in[1];
    const int*   pidx     = (const int*)d_in[2];
    const int*   batch    = (const int*)d_in[3];
    const float* enc_w1   = (const float*)d_in[4];
    const float* enc_b1   = (const float*)d_in[5];
    const float* enc_g    = (const float*)d_in[6];
    const float* enc_beta = (const float*)d_in[7];
    const float* enc_w2   = (const float*)d_in[8];
    const float* enc_b2   = (const float*)d_in[9];
    const float* pos_emb  = (const float*)d_in[10];
    const float* Wq       = (const float*)d_in[11];
    const float* bq       = (const float*)d_in[12];
    const float* Wk       = (const float*)d_in[13];
    const float* bk       = (const float*)d_in[14];
    const float* Wv       = (const float*)d_in[15];
    const float* bv       = (const float*)d_in[16];
    const float* mlp_w1   = (const float*)d_in[17];
    const float* mlp_b1   = (const float*)d_in[18];
    const float* mlp_g    = (const float*)d_in[19];
    const float* mlp_beta = (const float*)d_in[20];
    const float* mlp_w2   = (const float*)d_in[21];
    const float* mlp_b2   = (const float*)d_in[22];
    const float* cls_w1   = (const float*)d_in[23];
    const float* cls_b1   = (const float*)d_in[24];
    const float* cls_g    = (const float*)d_in[25];
    const float* cls_beta = (const float*)d_in[26];
    const float* cls_w2   = (const float*)d_in[27];
    const float* cls_b2   = (const float*)d_in[28];

    int n = in_sizes[2];            // 50000
    int e = in_sizes[1] / 2;        // 800000
    const int* row = ei;
    const int* col = ei + e;

    char* p = (char*)d_ws;
    auto alloc = [&](size_t bytes) -> void* {
        void* r = (void*)p;
        p += (bytes + 255) & ~(size_t)255;
        return r;
    };
    size_t NH = (size_t)n * HID;
    float* h             = (float*)alloc(NH * 4);          // fp32 residual stream
    unsigned short* h16  = (unsigned short*)alloc(NH * 2); // bf16 shadow of h
    unsigned short* a16  = (unsigned short*)alloc(NH * 2); // attn agg (bf16)
    unsigned short* m16  = (unsigned short*)alloc(NH * 2); // enc hidden / mlp hidden
    unsigned short* Qb   = (unsigned short*)alloc(NH * 2);
    unsigned short* Kb   = (unsigned short*)alloc(NH * 2);
    unsigned short* Vb   = (unsigned short*)alloc(NH * 2);
    float* partial = (float*)alloc((size_t)GRAPHS * PSPLIT * HID * 4);
    float* pooled  = (float*)alloc((size_t)GRAPHS * HID * 4);
    int* counts = (int*)alloc((size_t)n * 4);
    int* offs   = (int*)alloc((size_t)(n + 1) * 4);
    int* cur    = (int*)alloc((size_t)n * 4);
    int* ccol   = (int*)alloc((size_t)e * 4);
    int* bsum   = (int*)alloc(1024);
    int* gb     = (int*)alloc((GRAPHS + 1) * 4);
    unsigned short* wt_e1 = (unsigned short*)alloc((size_t)128 * 256 * 2);
    unsigned short* wt_e2 = (unsigned short*)alloc((size_t)256 * 256 * 2);
    unsigned short* wt_q  = (unsigned short*)alloc((size_t)4 * 256 * 256 * 2);
    unsigned short* wt_k  = (unsigned short*)alloc((size_t)4 * 256 * 256 * 2);
    unsigned short* wt_v  = (unsigned short*)alloc((size_t)4 * 256 * 256 * 2);
    unsigned short* wt_m1 = (unsigned short*)alloc((size_t)4 * 512 * 256 * 2);
    unsigned short* wt_m2 = (unsigned short*)alloc((size_t)4 * 256 * 256 * 2);

    int gblocks = (n + 63) / 64;
    int nb = (n + 255) / 256;

    // ---- weight prep ----
    wtrans_kernel<<<dim3(4, 8, 1),  256, 0, stream>>>(enc_w1, wt_e1, 128, 256);
    wtrans_kernel<<<dim3(8, 8, 1),  256, 0, stream>>>(enc_w2, wt_e2, 256, 256);
    wtrans_kernel<<<dim3(8, 8, 4),  256, 0, stream>>>(Wq,     wt_q,  256, 256);
    wtrans_kernel<<<dim3(8, 8, 4),  256, 0, stream>>>(Wk,     wt_k,  256, 256);
    wtrans_kernel<<<dim3(8, 8, 4),  256, 0, stream>>>(Wv,     wt_v,  256, 256);
    wtrans_kernel<<<dim3(16, 8, 4), 256, 0, stream>>>(mlp_w1, wt_m1, 512, 256);
    wtrans_kernel<<<dim3(8, 8, 4),  256, 0, stream>>>(mlp_w2, wt_m2, 256, 256);

    // ---- CSR build ----
    hipMemsetAsync(counts, 0, (size_t)n * 4, stream);
    hipMemsetAsync(cur, 0, (size_t)n * 4, stream);
    count_kernel<<<(e + 255) / 256, 256, 0, stream>>>(row, counts, e);
    scan1_kernel<<<nb, 256, 0, stream>>>(counts, offs, bsum, n);
    scan2_kernel<<<1, 256, 0, stream>>>(bsum, nb);
    scan3_kernel<<<nb, 256, 0, stream>>>(offs, bsum, n);
    scatter_kernel<<<(e + 255) / 256, 256, 0, stream>>>(row, col, offs, cur, ccol, e);
    bounds_kernel<<<1, 128, 0, stream>>>(batch, gb, n);

    // ---- encoder ----
    enc1_mfma<<<gblocks, 256, 0, stream>>>(x, wt_e1, enc_b1, enc_g, enc_beta, m16, n);
    gemm_bf16<256, 1, false, false, true, true, true><<<gblocks, 256, 0, stream>>>(
        m16, nullptr, wt_e2, enc_b2, nullptr, nullptr, nullptr, pos_emb, pidx, h, h16, n);

    // ---- attention layers ----
    for (int l = 0; l < 4; l++) {
        size_t wo = (size_t)l * 256 * 256;
        size_t bo = (size_t)l * HID;
        qkv_mfma_kernel<<<gblocks, 256, 0, stream>>>(
            h16, wt_q + wo, wt_k + wo, wt_v + wo, bq + bo, bk + bo, bv + bo,
            Qb, Kb, Vb, n);
        attn_bf16_kernel<<<n, 256, 0, stream>>>(Qb, Kb, Vb, offs, ccol, a16, n);
        gemm_bf16<256, 2, true, false, false, false, true><<<gblocks, 256, 0, stream>>>(
            h16, a16, wt_m1 + (size_t)l * 512 * 256, mlp_b1 + bo,
            mlp_g + bo, mlp_beta + bo, nullptr, nullptr, nullptr, nullptr, m16, n);
        gemm_bf16<256, 1, false, true, false, true, true><<<gblocks, 256, 0, stream>>>(
            m16, nullptr, wt_m2 + wo, mlp_b2 + bo, nullptr, nullptr, h, nullptr, nullptr,
            h, h16, n);
    }

    // ---- pool + classifier ----
    pool_partial_kernel<<<dim3(PSPLIT, GRAPHS), 256, 0, stream>>>(h, gb, partial);
    pool_reduce_kernel<<<GRAPHS, 256, 0, stream>>>(partial, gb, pooled);
    cls_kernel<<<GRAPHS, 256, 0, stream>>>(pooled, cls_w1, cls_b1, cls_g, cls_beta,
                                           cls_w2, cls_b2, (float*)d_out);
}